// Round 4
// baseline (5720.972 us; speedup 1.0000x reference)
//
#include <hip/hip_runtime.h>
#include <math.h>

#define T_STEPS 128
#define B_SZ 256
#define AD 16
#define ZD 32
#define KM 8
#define HID 128
#define G4H 512
#define NTHR 512
#define LDA 33   // padded stride for 32-col matrices
#define LDG 49   // padded stride for 48-col GJ augmented [S | CP]

// ws layout (float offsets)
#define WS_WIH0Q 0        // 8192  : [4][512][4]   W_ih0 transposed, float4-interleaved
#define WS_WHH0Q 8192     // 65536 : [32][512][4]
#define WS_WIH1Q 73728    // 65536
#define WS_WHH1Q 139264   // 65536
#define WS_BS0   204800   // 512   b_ih0+b_hh0
#define WS_BS1   205312   // 512
#define WS_Q     205824   // 1024  Q = QL QL^T + 1e-3 I
#define WS_R     206848   // 256   R = RL RL^T + 1e-3 I

__global__ void ssm_prep_kernel(const float* __restrict__ Wih0, const float* __restrict__ Whh0,
                                const float* __restrict__ Wih1, const float* __restrict__ Whh1,
                                const float* __restrict__ bih0, const float* __restrict__ bhh0,
                                const float* __restrict__ bih1, const float* __restrict__ bhh1,
                                const float* __restrict__ QL, const float* __restrict__ RL,
                                float* __restrict__ ws) {
  int tid = blockIdx.x * blockDim.x + threadIdx.x;
  int nt = gridDim.x * blockDim.x;
  for (int e = tid; e < G4H * AD; e += nt) {
    int j = e / AD, k = e % AD;
    ws[WS_WIH0Q + ((k >> 2) * G4H + j) * 4 + (k & 3)] = Wih0[e];
  }
  for (int e = tid; e < G4H * HID; e += nt) {
    int j = e >> 7, k = e & 127;
    int off = ((k >> 2) * G4H + j) * 4 + (k & 3);
    ws[WS_WHH0Q + off] = Whh0[e];
    ws[WS_WIH1Q + off] = Wih1[e];
    ws[WS_WHH1Q + off] = Whh1[e];
  }
  for (int e = tid; e < G4H; e += nt) {
    ws[WS_BS0 + e] = bih0[e] + bhh0[e];
    ws[WS_BS1 + e] = bih1[e] + bhh1[e];
  }
  for (int e = tid; e < ZD * ZD; e += nt) {
    int i = e >> 5, j = e & 31;
    float s = 0.f;
    for (int k = 0; k < ZD; ++k) s += QL[i * ZD + k] * QL[j * ZD + k];
    if (i == j) s += 0.001f;
    ws[WS_Q + e] = s;
  }
  for (int e = tid; e < AD * AD; e += nt) {
    int i = e >> 4, j = e & 15;
    float s = 0.f;
    for (int k = 0; k < AD; ++k) s += RL[i * AD + k] * RL[j * AD + k];
    if (i == j) s += 0.001f;
    ws[WS_R + e] = s;
  }
}

struct alignas(16) BS {
  float h0buf[2][HID];         // double-buffered h0 (parity hp)
  float h1[HID];
  float g[G4H];                // L1 gates
  float lgp[2 * KM];           // logit partials (wave0, wave1)
  float a[AD];
  float meanp[ZD], meant[ZD], r[AD];
  float P[ZD * LDA];           // cov_p
  float An[ZD * LDA];          // A_next
  float C[AD * LDA];           // C for current step
  float CP[AD * LDA];          // C @ cov_p
  float Aug[2][AD * LDG];      // GJ ping-pong [S | CP] -> [I | K^T]
  float Ct[ZD * LDA];          // cov_t (unsym)
  float ACt[ZD * LDA];         // A_next @ sym(cov_t)
};

__device__ __forceinline__ float sigm(float x) { return 1.0f / (1.0f + expf(-x)); }
__device__ __forceinline__ float d4(const float4& w, const float4& x) {
  return w.x * x.x + w.y * x.y + w.z * x.z + w.w * x.w;
}

__global__ void __launch_bounds__(NTHR) ssm_main_kernel(
    const float* __restrict__ as_, const float* __restrict__ AK, const float* __restrict__ CK,
    const float* __restrict__ initm, const float* __restrict__ initc,
    const float* __restrict__ Wout, const float* __restrict__ bout,
    const float* __restrict__ ws, float* __restrict__ out) {
  __shared__ BS s;
  const int tid = threadIdx.x;
  const int b = blockIdx.x;

  float* o_means = out;
  float* o_covs = o_means + (size_t)T_STEPS * B_SZ * ZD;
  float* o_nmean = o_covs + (size_t)T_STEPS * B_SZ * ZD * ZD;
  float* o_ncovs = o_nmean + (size_t)T_STEPS * B_SZ * ZD;
  float* o_As = o_ncovs + (size_t)T_STEPS * B_SZ * ZD * ZD;
  float* o_Cs = o_As + (size_t)(T_STEPS + 1) * B_SZ * ZD * ZD;
  float* o_a = o_Cs + (size_t)(T_STEPS + 1) * B_SZ * AD * ZD;

  const float* bs0 = ws + WS_BS0;
  const float* bs1 = ws + WS_BS1;
  const float* Qm = ws + WS_Q;
  const float* Rm = ws + WS_R;
  const float4* Wi0q = (const float4*)(ws + WS_WIH0Q);
  const float4* Wh0q = (const float4*)(ws + WS_WHH0Q);
  const float4* Wi1q = (const float4*)(ws + WS_WIH1Q);
  const float4* Wh1q = (const float4*)(ws + WS_WHH1Q);

  float c0r = 0.f, c1r = 0.f;   // register cell states (threads tid<128)
  int hp = 0;                   // h0 parity

  // ---- pre-loop init ----
  if (tid < HID) { s.h0buf[0][tid] = 0.f; s.h0buf[1][tid] = 0.f; s.h1[tid] = 0.f; }
  #pragma unroll
  for (int q = 0; q < 2; ++q) {
    int e = tid + q * NTHR;
    s.P[(e >> 5) * LDA + (e & 31)] = initc[e];
  }
  if (tid < ZD) s.meanp[tid] = initm[tid];
  {  // C0 = sum_k CK[k] (w0 = ones), o_Cs[0]
    float acc = 0.f;
    #pragma unroll
    for (int k = 0; k < KM; ++k) acc += CK[k * (AD * ZD) + tid];
    s.C[(tid >> 5) * LDA + (tid & 31)] = acc;
    o_Cs[(size_t)b * (AD * ZD) + tid] = acc;
  }
  #pragma unroll
  for (int q = 0; q < 2; ++q) {  // o_As[0] = sum_k AK[k]
    int e = tid + q * NTHR;
    float acc = 0.f;
    #pragma unroll
    for (int k = 0; k < KM; ++k) acc += AK[k * (ZD * ZD) + e];
    o_As[(size_t)b * (ZD * ZD) + e] = acc;
  }
  if (tid < AD) {  // a_0
    float v = as_[(size_t)b * AD + tid];
    s.a[tid] = v;
    o_a[(size_t)b * AD + tid] = v;
  }
  __syncthreads();

  for (int t = 0; t < T_STEPS; ++t) {
    const size_t tb = (size_t)t * B_SZ + b;
    const size_t tb2 = (size_t)(t + 1) * B_SZ + b;

    // ===== Phase B: [tid<128] gates0 (4 dots/unit) + h0/c0 local  |  [tid>=128] CP + r =====
    if (tid < HID) {
      const int u = tid;
      float a0 = bs0[u], a1 = bs0[HID + u], a2 = bs0[2 * HID + u], a3 = bs0[3 * HID + u];
      #pragma unroll
      for (int k4 = 0; k4 < 4; ++k4) {
        float4 x = *(const float4*)&s.a[k4 * 4];
        a0 += d4(Wi0q[k4 * G4H + u], x);
        a1 += d4(Wi0q[k4 * G4H + HID + u], x);
        a2 += d4(Wi0q[k4 * G4H + 2 * HID + u], x);
        a3 += d4(Wi0q[k4 * G4H + 3 * HID + u], x);
      }
      #pragma unroll 4
      for (int k4 = 0; k4 < 32; ++k4) {
        float4 x = *(const float4*)&s.h0buf[hp][k4 * 4];
        a0 += d4(Wh0q[k4 * G4H + u], x);
        a1 += d4(Wh0q[k4 * G4H + HID + u], x);
        a2 += d4(Wh0q[k4 * G4H + 2 * HID + u], x);
        a3 += d4(Wh0q[k4 * G4H + 3 * HID + u], x);
      }
      float ig = sigm(a0), fg = sigm(a1), gg = tanhf(a2), og = sigm(a3);
      c0r = fg * c0r + ig * gg;
      s.h0buf[hp ^ 1][u] = og * tanhf(c0r);
    } else {
      {  // CP elem e = tid-128
        int e = tid - 128;
        int i = e >> 5, jj = e & 31;
        float acc = 0.f;
        #pragma unroll
        for (int k = 0; k < ZD; ++k) acc += s.C[i * LDA + k] * s.P[k * LDA + jj];
        s.CP[i * LDA + jj] = acc;
      }
      if (tid < 256) {  // second CP elem e = tid+256
        int e = tid + 256;
        int i = e >> 5, jj = e & 31;
        float acc = 0.f;
        #pragma unroll
        for (int k = 0; k < ZD; ++k) acc += s.C[i * LDA + k] * s.P[k * LDA + jj];
        s.CP[i * LDA + jj] = acc;
      }
      if (tid >= 384 && tid < 384 + AD) {  // residual r
        int i = tid - 384;
        float acc = s.a[i];
        #pragma unroll
        for (int k = 0; k < ZD; ++k) acc -= s.C[i * LDA + k] * s.meanp[k];
        s.r[i] = acc;
      }
    }
    __syncthreads();

    // ===== Phase D: [waves 0-6] gates1  |  [wave 7] S-init + GJ -> K^T  |  a prefetch =====
    if (tid < 448) {
      if (t < T_STEPS - 1 && tid >= 384 && tid < 384 + AD) {  // prefetch a_{t+1}
        int i = tid - 384;
        float v = as_[tb2 * AD + i];
        s.a[i] = v;
        o_a[tb2 * AD + i] = v;
      }
      {
        const int j = tid;
        float acc = bs1[j];
        #pragma unroll 8
        for (int k4 = 0; k4 < 32; ++k4) {
          float4 x0 = *(const float4*)&s.h0buf[hp ^ 1][k4 * 4];
          float4 x1 = *(const float4*)&s.h1[k4 * 4];
          acc += d4(Wi1q[k4 * G4H + j], x0) + d4(Wh1q[k4 * G4H + j], x1);
        }
        s.g[j] = acc;
      }
      if (tid < 64) {
        const int j = 448 + tid;
        float acc = bs1[j];
        #pragma unroll 8
        for (int k4 = 0; k4 < 32; ++k4) {
          float4 x0 = *(const float4*)&s.h0buf[hp ^ 1][k4 * 4];
          float4 x1 = *(const float4*)&s.h1[k4 * 4];
          acc += d4(Wi1q[k4 * G4H + j], x0) + d4(Wh1q[k4 * G4H + j], x1);
        }
        s.g[j] = acc;
      }
    } else {
      // wave 7: build Aug[0] = [S | CP], then 16 GJ iterations (wave-synchronous)
      const int l = tid - 448;
      const int i = l >> 2, cg = l & 3;  // row i, column group cg*12..cg*12+11
      #pragma unroll
      for (int m = 0; m < 12; ++m) {
        int k = cg * 12 + m;
        float v;
        if (k < AD) {
          v = Rm[i * AD + k];
          #pragma unroll
          for (int q = 0; q < ZD; ++q) v += s.CP[i * LDA + q] * s.C[k * LDA + q];
        } else {
          v = s.CP[i * LDA + (k - AD)];
        }
        s.Aug[0][i * LDG + k] = v;
      }
      __builtin_amdgcn_wave_barrier();
      for (int j = 0; j < AD; ++j) {
        volatile const float* src = s.Aug[j & 1];
        volatile float* dst = s.Aug[(j + 1) & 1];
        float pinv = 1.0f / src[j * LDG + j];
        float fp = src[i * LDG + j] * pinv;
        #pragma unroll
        for (int m = 0; m < 12; ++m) {
          int k = cg * 12 + m;
          float v = src[i * LDG + k];
          float pj = src[j * LDG + k];
          dst[i * LDG + k] = (i == j) ? v * pinv : fmaf(-fp, pj, v);
        }
        __builtin_amdgcn_wave_barrier();
      }
    }
    __syncthreads();
    const float* KT = s.Aug[0];  // K^T[k][i] at [k*LDG + 16 + i], k<16, i<32

    // ===== Phase E: [tid<128] h1/c1 + logit partials | [128..160) mean_t | all cov_t =====
    if (tid < HID) {
      const int u = tid;
      float ig = sigm(s.g[u]);
      float fg = sigm(s.g[HID + u]);
      float gg = tanhf(s.g[2 * HID + u]);
      float og = sigm(s.g[3 * HID + u]);
      c1r = fg * c1r + ig * gg;
      float h1u = og * tanhf(c1r);
      s.h1[u] = h1u;
      int w2 = tid >> 6, lane = tid & 63;
      #pragma unroll
      for (int gi = 0; gi < KM; ++gi) {
        float p = Wout[gi * HID + u] * h1u;
        #pragma unroll
        for (int m = 32; m >= 1; m >>= 1) p += __shfl_xor(p, m);
        if (lane == 0) s.lgp[w2 * KM + gi] = p;
      }
    }
    if (tid >= 128 && tid < 128 + ZD) {  // mean_t
      int i = tid - 128;
      float acc = s.meanp[i];
      #pragma unroll
      for (int k = 0; k < AD; ++k) acc += KT[k * LDG + AD + i] * s.r[k];
      s.meant[i] = acc;
      o_means[tb * ZD + i] = acc;
    }
    #pragma unroll
    for (int q = 0; q < 2; ++q) {  // cov_t = P - K @ CP
      int e = tid + q * NTHR;
      int i = e >> 5, jj = e & 31;
      float acc = 0.f;
      #pragma unroll
      for (int k = 0; k < AD; ++k) acc += KT[k * LDG + AD + i] * s.CP[k * LDA + jj];
      s.Ct[i * LDA + jj] = s.P[i * LDA + jj] - acc;
    }
    __syncthreads();

    // ===== Phase G: softmax (per-thread) + A_next + C_next + covs out =====
    {
      float lg[KM];
      float mx = -1e30f;
      #pragma unroll
      for (int k = 0; k < KM; ++k) {
        lg[k] = s.lgp[k] + s.lgp[KM + k] + bout[k];
        mx = fmaxf(mx, lg[k]);
      }
      float sum = 0.f;
      #pragma unroll
      for (int k = 0; k < KM; ++k) { lg[k] = expf(lg[k] - mx); sum += lg[k]; }
      float inv = 1.0f / sum;
      #pragma unroll
      for (int k = 0; k < KM; ++k) lg[k] *= inv;
      #pragma unroll
      for (int q = 0; q < 2; ++q) {  // A_next + o_As[t+1]
        int e = tid + q * NTHR;
        float acc = 0.f;
        #pragma unroll
        for (int k = 0; k < KM; ++k) acc += lg[k] * AK[k * (ZD * ZD) + e];
        s.An[(e >> 5) * LDA + (e & 31)] = acc;
        o_As[tb2 * (ZD * ZD) + e] = acc;
      }
      {  // C_next + o_Cs[t+1]
        float acc = 0.f;
        #pragma unroll
        for (int k = 0; k < KM; ++k) acc += lg[k] * CK[k * (AD * ZD) + tid];
        s.C[(tid >> 5) * LDA + (tid & 31)] = acc;
        o_Cs[tb2 * (AD * ZD) + tid] = acc;
      }
      #pragma unroll
      for (int q = 0; q < 2; ++q) {  // covs out = sym(Ct)
        int e = tid + q * NTHR;
        int i = e >> 5, jj = e & 31;
        o_covs[tb * (ZD * ZD) + e] = 0.5f * (s.Ct[i * LDA + jj] + s.Ct[jj * LDA + i]);
      }
    }
    __syncthreads();

    // ===== Phase H: ACt = An @ sym(Ct) + meanp' = An @ mean_t =====
    if (tid >= 128 && tid < 128 + ZD) {
      int i = tid - 128;
      float acc = 0.f;
      #pragma unroll
      for (int k = 0; k < ZD; ++k) acc += s.An[i * LDA + k] * s.meant[k];
      s.meanp[i] = acc;
      o_nmean[tb * ZD + i] = acc;
    }
    #pragma unroll
    for (int q = 0; q < 2; ++q) {
      int e = tid + q * NTHR;
      int i = e >> 5, jj = e & 31;
      float acc = 0.f;
      #pragma unroll
      for (int k = 0; k < ZD; ++k)
        acc += s.An[i * LDA + k] * (0.5f * (s.Ct[k * LDA + jj] + s.Ct[jj * LDA + k]));
      s.ACt[i * LDA + jj] = acc;
    }
    __syncthreads();

    // ===== Phase I: cov_p' = sym(ACt @ An^T) + Q  (fused sym) =====
    #pragma unroll
    for (int q = 0; q < 2; ++q) {
      int e = tid + q * NTHR;
      int i = e >> 5, jj = e & 31;
      float acc = 0.f;
      #pragma unroll
      for (int k = 0; k < ZD; ++k)
        acc += s.ACt[i * LDA + k] * s.An[jj * LDA + k] + s.ACt[jj * LDA + k] * s.An[i * LDA + k];
      float v = 0.5f * acc + Qm[e];
      s.P[i * LDA + jj] = v;
      o_ncovs[tb * (ZD * ZD) + e] = v;
    }
    hp ^= 1;
    __syncthreads();
  }
}

extern "C" void kernel_launch(void* const* d_in, const int* in_sizes, int n_in,
                              void* d_out, int out_size, void* d_ws, size_t ws_size,
                              hipStream_t stream) {
  const float* as_ = (const float*)d_in[0];
  const float* AK = (const float*)d_in[1];
  const float* CK = (const float*)d_in[2];
  const float* QL = (const float*)d_in[3];
  const float* RL = (const float*)d_in[4];
  const float* initm = (const float*)d_in[5];
  const float* initc = (const float*)d_in[6];
  const float* Wih0 = (const float*)d_in[7];
  const float* Whh0 = (const float*)d_in[8];
  const float* bih0 = (const float*)d_in[9];
  const float* bhh0 = (const float*)d_in[10];
  const float* Wih1 = (const float*)d_in[11];
  const float* Whh1 = (const float*)d_in[12];
  const float* bih1 = (const float*)d_in[13];
  const float* bhh1 = (const float*)d_in[14];
  const float* Wout = (const float*)d_in[15];
  const float* bout = (const float*)d_in[16];
  float* ws = (float*)d_ws;
  float* out = (float*)d_out;

  ssm_prep_kernel<<<256, 256, 0, stream>>>(Wih0, Whh0, Wih1, Whh1, bih0, bhh0, bih1, bhh1,
                                           QL, RL, ws);
  ssm_main_kernel<<<B_SZ, NTHR, 0, stream>>>(as_, AK, CK, initm, initc, Wout, bout, ws, out);
}

// Round 5
// 4365.603 us; speedup vs baseline: 1.3105x; 1.3105x over previous
//
#include <hip/hip_runtime.h>
#include <hip/hip_fp16.h>
#include <math.h>

#define T_STEPS 128
#define B_SZ 256
#define AD 16
#define ZD 32
#define KM 8
#define HID 128
#define G4H 512
#define NTHR 512

// ws layout (4-byte word offsets)
#define WS_WQ   0         // 192*512 u32 : packed f16 pairs, [d][thread j]
                          //   d 0..63 = W_hh0 row j, d 64..127 = W_ih1 row j, d 128..191 = W_hh1 row j
#define WS_WI0  98304     // 8*512 u32 : W_ih0 row j packed pairs, [k][j]
#define WS_BS0  102400    // 512  b_ih0+b_hh0
#define WS_BS1  102912    // 512  b_ih1+b_hh1
#define WS_Q    103424    // 1024 Q = QL QL^T + 1e-3 I
#define WS_R    104448    // 256  R = RL RL^T + 1e-3 I

__device__ __forceinline__ unsigned pk16(float lo, float hi) {
  unsigned a = __half_as_ushort(__float2half_rn(lo));
  unsigned b = __half_as_ushort(__float2half_rn(hi));
  return a | (b << 16);
}

__global__ void ssm_prep_kernel(const float* __restrict__ Wih0, const float* __restrict__ Whh0,
                                const float* __restrict__ Wih1, const float* __restrict__ Whh1,
                                const float* __restrict__ bih0, const float* __restrict__ bhh0,
                                const float* __restrict__ bih1, const float* __restrict__ bhh1,
                                const float* __restrict__ QL, const float* __restrict__ RL,
                                float* __restrict__ ws) {
  unsigned* wsu = (unsigned*)ws;
  int tid = blockIdx.x * blockDim.x + threadIdx.x;
  int nt = gridDim.x * blockDim.x;
  for (int j = tid; j < G4H; j += nt) {
    for (int d = 0; d < 64; ++d) {
      wsu[WS_WQ + d * 512 + j]         = pk16(Whh0[j * 128 + 2 * d], Whh0[j * 128 + 2 * d + 1]);
      wsu[WS_WQ + (64 + d) * 512 + j]  = pk16(Wih1[j * 128 + 2 * d], Wih1[j * 128 + 2 * d + 1]);
      wsu[WS_WQ + (128 + d) * 512 + j] = pk16(Whh1[j * 128 + 2 * d], Whh1[j * 128 + 2 * d + 1]);
    }
    for (int k = 0; k < 8; ++k)
      wsu[WS_WI0 + k * 512 + j] = pk16(Wih0[j * 16 + 2 * k], Wih0[j * 16 + 2 * k + 1]);
    ws[WS_BS0 + j] = bih0[j] + bhh0[j];
    ws[WS_BS1 + j] = bih1[j] + bhh1[j];
  }
  for (int e = tid; e < ZD * ZD; e += nt) {
    int i = e >> 5, j = e & 31;
    float s = 0.f;
    for (int k = 0; k < ZD; ++k) s += QL[i * ZD + k] * QL[j * ZD + k];
    if (i == j) s += 0.001f;
    ws[WS_Q + e] = s;
  }
  for (int e = tid; e < AD * AD; e += nt) {
    int i = e >> 4, j = e & 15;
    float s = 0.f;
    for (int k = 0; k < AD; ++k) s += RL[i * AD + k] * RL[j * AD + k];
    if (i == j) s += 0.001f;
    ws[WS_R + e] = s;
  }
}

struct alignas(16) BS {
  unsigned wi0[8 * 512];   // W_ih0 packed pairs [k][j]
  float wout[KM * HID];    // f32
  float Q[ZD * ZD];
  float R[AD * AD];
  float bout_s[KM];
  unsigned ap[8];          // a_t packed f16 pairs
  float af[AD];            // a_t f32
  unsigned h0p[64];        // h0 packed f16 pairs
  unsigned h1p[64];
  float g[G4H];            // gates (L0 then L1)
  float lgp[16];           // logit partials (wave0, wave1)
  float meanp[ZD], meant[ZD], r[AD];
  float P[ZD * 33];
  float An[ZD * 33];
  float Ct[ZD * 33];
  float ACt[ZD * 33];
  float C[AD * 33];
  float CP[AD * 33];
  float KT[AD * 33];       // K^T [k][i]
  float SA[AD * 17];       // S   [i][jj]
};

__device__ __forceinline__ float sigm(float x) { return 1.0f / (1.0f + expf(-x)); }

__device__ __forceinline__ float dot2f(unsigned a, unsigned b, float c) {
#if __has_builtin(__builtin_amdgcn_fdot2)
  typedef _Float16 h2 __attribute__((ext_vector_type(2)));
  union U { unsigned u; h2 h; };
  U ua, ub; ua.u = a; ub.u = b;
  return __builtin_amdgcn_fdot2(ua.h, ub.h, c, false);
#else
  union U { unsigned u; _Float16 h[2]; };
  U ua, ub; ua.u = a; ub.u = b;
  return c + (float)ua.h[0] * (float)ub.h[0] + (float)ua.h[1] * (float)ub.h[1];
#endif
}

__global__ void __launch_bounds__(NTHR, 2) ssm_main_kernel(
    const float* __restrict__ as_, const float* __restrict__ AK, const float* __restrict__ CK,
    const float* __restrict__ initm, const float* __restrict__ initc,
    const float* __restrict__ Wout, const float* __restrict__ bout,
    const float* __restrict__ ws, float* __restrict__ out) {
  __shared__ BS s;
  const int tid = threadIdx.x;
  const int b = blockIdx.x;
  const unsigned* wsu = (const unsigned*)ws;

  float* o_means = out;
  float* o_covs = o_means + (size_t)T_STEPS * B_SZ * ZD;
  float* o_nmean = o_covs + (size_t)T_STEPS * B_SZ * ZD * ZD;
  float* o_ncovs = o_nmean + (size_t)T_STEPS * B_SZ * ZD;
  float* o_As = o_ncovs + (size_t)T_STEPS * B_SZ * ZD * ZD;
  float* o_Cs = o_As + (size_t)(T_STEPS + 1) * B_SZ * ZD * ZD;
  float* o_a = o_Cs + (size_t)(T_STEPS + 1) * B_SZ * AD * ZD;

  // ---- persistent register weights: 192 packed-f16-pair dwords ----
  unsigned wh[192];
  #pragma unroll
  for (int d = 0; d < 192; ++d) wh[d] = wsu[WS_WQ + d * 512 + tid];
  const float bs0r = ws[WS_BS0 + tid];
  const float bs1r = ws[WS_BS1 + tid];

  float c0r = 0.f, c1r = 0.f;  // cell states (threads tid<128)

  // ---- LDS init ----
  for (int e = tid; e < 8 * 512; e += NTHR) s.wi0[e] = wsu[WS_WI0 + e];
  for (int e = tid; e < KM * HID; e += NTHR) s.wout[e] = Wout[e];
  for (int e = tid; e < ZD * ZD; e += NTHR) s.Q[e] = ws[WS_Q + e];
  if (tid < AD * AD) s.R[tid] = ws[WS_R + tid];
  if (tid < KM) s.bout_s[tid] = bout[tid];
  if (tid < 64) { s.h0p[tid] = 0u; s.h1p[tid] = 0u; }
  #pragma unroll
  for (int q = 0; q < 2; ++q) {
    int e = tid + q * NTHR;
    s.P[(e >> 5) * 33 + (e & 31)] = initc[e];
  }
  if (tid < ZD) s.meanp[tid] = initm[tid];
  if (tid < AD) {
    float v = as_[(size_t)b * AD + tid];
    s.af[tid] = v;
    ((__half*)s.ap)[tid] = __float2half_rn(v);
    o_a[(size_t)b * AD + tid] = v;
  }
  {  // C0 = sum_k CK[k]  (w0 = ones)
    float acc = 0.f;
    #pragma unroll
    for (int k = 0; k < KM; ++k) acc += CK[k * (AD * ZD) + tid];
    s.C[(tid >> 5) * 33 + (tid & 31)] = acc;
    o_Cs[(size_t)b * (AD * ZD) + tid] = acc;
  }
  #pragma unroll
  for (int q = 0; q < 2; ++q) {  // o_As[0] = sum_k AK[k]
    int e = tid + q * NTHR;
    float acc = 0.f;
    #pragma unroll
    for (int k = 0; k < KM; ++k) acc += AK[k * (ZD * ZD) + e];
    o_As[(size_t)b * (ZD * ZD) + e] = acc;
  }
  __syncthreads();

  for (int t = 0; t < T_STEPS; ++t) {
    const size_t tb = (size_t)t * B_SZ + b;
    const size_t tb2 = (size_t)(t + 1) * B_SZ + b;

    // ===== A: L0 gate (reg weights, dot2) + CP = C@P + r =====
    {
      float acc = bs0r;
      #pragma unroll
      for (int k = 0; k < 8; ++k) acc = dot2f(s.ap[k], s.wi0[k * 512 + tid], acc);
      #pragma unroll
      for (int k4 = 0; k4 < 16; ++k4) {
        uint4 hv = *(const uint4*)&s.h0p[k4 * 4];
        acc = dot2f(hv.x, wh[k4 * 4 + 0], acc);
        acc = dot2f(hv.y, wh[k4 * 4 + 1], acc);
        acc = dot2f(hv.z, wh[k4 * 4 + 2], acc);
        acc = dot2f(hv.w, wh[k4 * 4 + 3], acc);
      }
      s.g[tid] = acc;
    }
    {
      int i = tid >> 5, jj = tid & 31;
      float acc = 0.f;
      #pragma unroll
      for (int k = 0; k < ZD; ++k) acc += s.C[i * 33 + k] * s.P[k * 33 + jj];
      s.CP[i * 33 + jj] = acc;
    }
    if (tid >= 480 && tid < 480 + AD) {
      int i = tid - 480;
      float acc = s.af[i];
      #pragma unroll
      for (int k = 0; k < ZD; ++k) acc -= s.C[i * 33 + k] * s.meanp[k];
      s.r[i] = acc;
    }
    __syncthreads();

    // ===== B: h0/c0 update + S = CP C^T + R =====
    if (tid < HID) {
      float ig = sigm(s.g[tid]);
      float fg = sigm(s.g[HID + tid]);
      float gg = tanhf(s.g[2 * HID + tid]);
      float og = sigm(s.g[3 * HID + tid]);
      c0r = fg * c0r + ig * gg;
      float h0 = og * tanhf(c0r);
      ((__half*)s.h0p)[tid] = __float2half_rn(h0);
    }
    if (tid < AD * AD) {
      int i = tid >> 4, jj = tid & 15;
      float acc = s.R[i * AD + jj];
      #pragma unroll
      for (int k = 0; k < ZD; ++k) acc += s.CP[i * 33 + k] * s.C[jj * 33 + k];
      s.SA[i * 17 + jj] = acc;
    }
    __syncthreads();

    // ===== C: L1 gate (reg weights) =====
    {
      float acc = bs1r;
      #pragma unroll
      for (int k4 = 0; k4 < 16; ++k4) {
        uint4 hv = *(const uint4*)&s.h0p[k4 * 4];
        acc = dot2f(hv.x, wh[64 + k4 * 4 + 0], acc);
        acc = dot2f(hv.y, wh[64 + k4 * 4 + 1], acc);
        acc = dot2f(hv.z, wh[64 + k4 * 4 + 2], acc);
        acc = dot2f(hv.w, wh[64 + k4 * 4 + 3], acc);
      }
      #pragma unroll
      for (int k4 = 0; k4 < 16; ++k4) {
        uint4 hv = *(const uint4*)&s.h1p[k4 * 4];
        acc = dot2f(hv.x, wh[128 + k4 * 4 + 0], acc);
        acc = dot2f(hv.y, wh[128 + k4 * 4 + 1], acc);
        acc = dot2f(hv.z, wh[128 + k4 * 4 + 2], acc);
        acc = dot2f(hv.w, wh[128 + k4 * 4 + 3], acc);
      }
      s.g[tid] = acc;
    }
    __syncthreads();

    // ===== D: [tid<128] h1/c1 + logit partials  |  [wave 7] register GJ -> K^T =====
    if (tid < HID) {
      float ig = sigm(s.g[tid]);
      float fg = sigm(s.g[HID + tid]);
      float gg = tanhf(s.g[2 * HID + tid]);
      float og = sigm(s.g[3 * HID + tid]);
      c1r = fg * c1r + ig * gg;
      float h1u = og * tanhf(c1r);
      ((__half*)s.h1p)[tid] = __float2half_rn(h1u);
      int w2 = tid >> 6, lane = tid & 63;
      #pragma unroll
      for (int gi = 0; gi < KM; ++gi) {
        float p = s.wout[gi * HID + tid] * h1u;
        #pragma unroll
        for (int m = 32; m >= 1; m >>= 1) p += __shfl_xor(p, m);
        if (lane == 0) s.lgp[w2 * KM + gi] = p;
      }
    } else if (tid >= 448) {
      // wave-synchronous GJ in registers: lane l holds column l of [S | CP]
      const int l = tid & 63;
      float col[16];
      #pragma unroll
      for (int i = 0; i < AD; ++i)
        col[i] = (l < AD) ? s.SA[i * 17 + l] : s.CP[i * 33 + ((l - AD) & 31)];
      #pragma unroll
      for (int j = 0; j < AD; ++j) {
        float pd = __shfl(col[j], j);
        float pinv = 1.0f / pd;
        float oldj = col[j];
        #pragma unroll
        for (int i = 0; i < AD; ++i) {
          if (i == j) continue;
          float fi = __shfl(col[i], j);
          col[i] = fmaf(-(fi * pinv), oldj, col[i]);
        }
        col[j] = oldj * pinv;
      }
      if (l >= AD && l < AD + ZD) {
        #pragma unroll
        for (int k = 0; k < AD; ++k) s.KT[k * 33 + (l - AD)] = col[k];
      }
    }
    __syncthreads();

    // ===== E: softmax + A_next/C_next einsum + cov_t + mean_t =====
    {
      float lg[KM];
      float mx = -1e30f;
      #pragma unroll
      for (int k = 0; k < KM; ++k) {
        lg[k] = s.lgp[k] + s.lgp[KM + k] + s.bout_s[k];
        mx = fmaxf(mx, lg[k]);
      }
      float sum = 0.f;
      #pragma unroll
      for (int k = 0; k < KM; ++k) { lg[k] = expf(lg[k] - mx); sum += lg[k]; }
      float inv = 1.0f / sum;
      #pragma unroll
      for (int k = 0; k < KM; ++k) lg[k] *= inv;
      #pragma unroll
      for (int q = 0; q < 2; ++q) {
        int e = tid + q * NTHR;
        float acc = 0.f;
        #pragma unroll
        for (int k = 0; k < KM; ++k) acc += lg[k] * AK[k * (ZD * ZD) + e];
        s.An[(e >> 5) * 33 + (e & 31)] = acc;
        o_As[tb2 * (ZD * ZD) + e] = acc;
      }
      {
        float acc = 0.f;
        #pragma unroll
        for (int k = 0; k < KM; ++k) acc += lg[k] * CK[k * (AD * ZD) + tid];
        s.C[(tid >> 5) * 33 + (tid & 31)] = acc;
        o_Cs[tb2 * (AD * ZD) + tid] = acc;
      }
    }
    #pragma unroll
    for (int q = 0; q < 2; ++q) {  // cov_t = P - K @ CP
      int e = tid + q * NTHR;
      int i = e >> 5, jj = e & 31;
      float acc = 0.f;
      #pragma unroll
      for (int k = 0; k < AD; ++k) acc += s.KT[k * 33 + i] * s.CP[k * 33 + jj];
      s.Ct[i * 33 + jj] = s.P[i * 33 + jj] - acc;
    }
    if (tid >= 128 && tid < 128 + ZD) {  // mean_t
      int i = tid - 128;
      float acc = s.meanp[i];
      #pragma unroll
      for (int k = 0; k < AD; ++k) acc += s.KT[k * 33 + i] * s.r[k];
      s.meant[i] = acc;
      o_means[tb * ZD + i] = acc;
    }
    __syncthreads();

    // ===== F: covs out = sym(Ct), ACt = An @ sym(Ct), meanp' = An @ mean_t =====
    #pragma unroll
    for (int q = 0; q < 2; ++q) {
      int e = tid + q * NTHR;
      int i = e >> 5, jj = e & 31;
      o_covs[tb * (ZD * ZD) + e] = 0.5f * (s.Ct[i * 33 + jj] + s.Ct[jj * 33 + i]);
      float acc = 0.f;
      #pragma unroll
      for (int k = 0; k < ZD; ++k)
        acc += s.An[i * 33 + k] * (0.5f * (s.Ct[k * 33 + jj] + s.Ct[jj * 33 + k]));
      s.ACt[i * 33 + jj] = acc;
    }
    if (tid >= 160 && tid < 160 + ZD) {
      int i = tid - 160;
      float acc = 0.f;
      #pragma unroll
      for (int k = 0; k < ZD; ++k) acc += s.An[i * 33 + k] * s.meant[k];
      s.meanp[i] = acc;
      o_nmean[tb * ZD + i] = acc;
    }
    __syncthreads();

    // ===== G: cov_p' = sym(ACt @ An^T) + Q  + a_{t+1} prefetch =====
    #pragma unroll
    for (int q = 0; q < 2; ++q) {
      int e = tid + q * NTHR;
      int i = e >> 5, jj = e & 31;
      float acc = 0.f;
      #pragma unroll
      for (int k = 0; k < ZD; ++k)
        acc += s.ACt[i * 33 + k] * s.An[jj * 33 + k] + s.ACt[jj * 33 + k] * s.An[i * 33 + k];
      float v = 0.5f * acc + s.Q[e];
      s.P[i * 33 + jj] = v;
      o_ncovs[tb * (ZD * ZD) + e] = v;
    }
    if (t < T_STEPS - 1 && tid >= 416 && tid < 416 + AD) {
      int i = tid - 416;
      float v = as_[tb2 * AD + i];
      s.af[i] = v;
      ((__half*)s.ap)[i] = __float2half_rn(v);
      o_a[tb2 * AD + i] = v;
    }
    __syncthreads();
  }
}

extern "C" void kernel_launch(void* const* d_in, const int* in_sizes, int n_in,
                              void* d_out, int out_size, void* d_ws, size_t ws_size,
                              hipStream_t stream) {
  const float* as_ = (const float*)d_in[0];
  const float* AK = (const float*)d_in[1];
  const float* CK = (const float*)d_in[2];
  const float* QL = (const float*)d_in[3];
  const float* RL = (const float*)d_in[4];
  const float* initm = (const float*)d_in[5];
  const float* initc = (const float*)d_in[6];
  const float* Wih0 = (const float*)d_in[7];
  const float* Whh0 = (const float*)d_in[8];
  const float* bih0 = (const float*)d_in[9];
  const float* bhh0 = (const float*)d_in[10];
  const float* Wih1 = (const float*)d_in[11];
  const float* Whh1 = (const float*)d_in[12];
  const float* bih1 = (const float*)d_in[13];
  const float* bhh1 = (const float*)d_in[14];
  const float* Wout = (const float*)d_in[15];
  const float* bout = (const float*)d_in[16];
  float* ws = (float*)d_ws;
  float* out = (float*)d_out;

  ssm_prep_kernel<<<16, 256, 0, stream>>>(Wih0, Whh0, Wih1, Whh1, bih0, bhh0, bih1, bhh1,
                                          QL, RL, ws);
  ssm_main_kernel<<<B_SZ, NTHR, 0, stream>>>(as_, AK, CK, initm, initc, Wout, bout, ws, out);
}

// Round 6
// 3417.403 us; speedup vs baseline: 1.6741x; 1.2775x over previous
//
#include <hip/hip_runtime.h>
#include <hip/hip_fp16.h>
#include <math.h>

#define T_STEPS 128
#define B_SZ 256
#define AD 16
#define ZD 32
#define KM 8
#define HID 128
#define G4H 512
#define NTHR 512

// ws layout (4-byte word offsets)
// WS_WQ: 48*512*4 u32, packed f16 pairs, [d4][thread j][m] (uint4 per thread per d4)
//   d4  0..15 : W_hh0 row j, dword d4*4+m = cols (8*d4+2m, 8*d4+2m+1)
//   d4 16..31 : W_ih1 row j
//   d4 32..47 : W_hh1 row j
#define WS_WQ   0
#define WS_WI0  98304     // 8*512 u32 : W_ih0 row j packed pairs, [k][j]
#define WS_BS0  102400    // 512  b_ih0+b_hh0
#define WS_BS1  102912    // 512  b_ih1+b_hh1
#define WS_Q    103424    // 1024 Q = QL QL^T + 1e-3 I
#define WS_R    104448    // 256  R = RL RL^T + 1e-3 I

__device__ __forceinline__ unsigned pk16(float lo, float hi) {
  unsigned a = __half_as_ushort(__float2half_rn(lo));
  unsigned b = __half_as_ushort(__float2half_rn(hi));
  return a | (b << 16);
}

__global__ void ssm_prep_kernel(const float* __restrict__ Wih0, const float* __restrict__ Whh0,
                                const float* __restrict__ Wih1, const float* __restrict__ Whh1,
                                const float* __restrict__ bih0, const float* __restrict__ bhh0,
                                const float* __restrict__ bih1, const float* __restrict__ bhh1,
                                const float* __restrict__ QL, const float* __restrict__ RL,
                                float* __restrict__ ws) {
  unsigned* wsu = (unsigned*)ws;
  int tid = blockIdx.x * blockDim.x + threadIdx.x;
  int nt = gridDim.x * blockDim.x;
  for (int j = tid; j < G4H; j += nt) {
    for (int d4 = 0; d4 < 48; ++d4) {
      for (int m = 0; m < 4; ++m) {
        int dd = (d4 & 15) * 4 + m;  // 0..63 dword within matrix
        const float* src = (d4 < 16) ? Whh0 : (d4 < 32) ? Wih1 : Whh1;
        wsu[WS_WQ + (d4 * 512 + j) * 4 + m] =
            pk16(src[j * 128 + 2 * dd], src[j * 128 + 2 * dd + 1]);
      }
    }
    for (int k = 0; k < 8; ++k)
      wsu[WS_WI0 + k * 512 + j] = pk16(Wih0[j * 16 + 2 * k], Wih0[j * 16 + 2 * k + 1]);
    ws[WS_BS0 + j] = bih0[j] + bhh0[j];
    ws[WS_BS1 + j] = bih1[j] + bhh1[j];
  }
  for (int e = tid; e < ZD * ZD; e += nt) {
    int i = e >> 5, j = e & 31;
    float s = 0.f;
    for (int k = 0; k < ZD; ++k) s += QL[i * ZD + k] * QL[j * ZD + k];
    if (i == j) s += 0.001f;
    ws[WS_Q + e] = s;
  }
  for (int e = tid; e < AD * AD; e += nt) {
    int i = e >> 4, j = e & 15;
    float s = 0.f;
    for (int k = 0; k < AD; ++k) s += RL[i * AD + k] * RL[j * AD + k];
    if (i == j) s += 0.001f;
    ws[WS_R + e] = s;
  }
}

struct alignas(16) BS {
  unsigned wi0[8 * 512];   // W_ih0 packed pairs [k][j]
  float wout[KM * HID];
  float Q[ZD * ZD];
  float R[AD * AD];
  float bout_s[KM];
  unsigned ap[8];          // a_t packed f16 pairs
  float af[AD];            // a_t f32
  unsigned h0p[64];        // h0 packed f16 pairs (16B aligned)
  unsigned h1p[64];
  float g[G4H];            // gates (L0 then L1)
  float lgp[16];           // logit partials (wave0, wave1)
  float meanp[ZD], meant[ZD], r[AD];
  float P[ZD * 33];
  float An[ZD * 33];
  float Ct[ZD * 33];
  float ACt[ZD * 33];
  float C[AD * 33];
  float CP[AD * 33];
  float KT[AD * 33];       // K^T [k][i]
  float SA[AD * 17];       // S   [i][jj]
};

__device__ __forceinline__ float sigm(float x) { return 1.0f / (1.0f + expf(-x)); }

__device__ __forceinline__ float dot2f(unsigned a, unsigned b, float c) {
#if __has_builtin(__builtin_amdgcn_fdot2)
  typedef _Float16 h2 __attribute__((ext_vector_type(2)));
  union U { unsigned u; h2 h; };
  U ua, ub; ua.u = a; ub.u = b;
  return __builtin_amdgcn_fdot2(ua.h, ub.h, c, false);
#else
  union U { unsigned u; _Float16 h[2]; };
  U ua, ub; ua.u = a; ub.u = b;
  return c + (float)ua.h[0] * (float)ub.h[0] + (float)ua.h[1] * (float)ub.h[1];
#endif
}

__global__ void __launch_bounds__(NTHR, 2) ssm_main_kernel(
    const float* __restrict__ as_, const float* __restrict__ AK, const float* __restrict__ CK,
    const float* __restrict__ initm, const float* __restrict__ initc,
    const float* __restrict__ Wout, const float* __restrict__ bout,
    const float* __restrict__ ws, float* __restrict__ out) {
  __shared__ BS s;
  const int tid = threadIdx.x;
  const int b = blockIdx.x;
  const unsigned* wsu = (const unsigned*)ws;
  const uint4* Wg = (const uint4*)(wsu + WS_WQ);  // [d4][j] uint4

  float* o_means = out;
  float* o_covs = o_means + (size_t)T_STEPS * B_SZ * ZD;
  float* o_nmean = o_covs + (size_t)T_STEPS * B_SZ * ZD * ZD;
  float* o_ncovs = o_nmean + (size_t)T_STEPS * B_SZ * ZD;
  float* o_As = o_ncovs + (size_t)T_STEPS * B_SZ * ZD * ZD;
  float* o_Cs = o_As + (size_t)(T_STEPS + 1) * B_SZ * ZD * ZD;
  float* o_a = o_Cs + (size_t)(T_STEPS + 1) * B_SZ * AD * ZD;

  const float bs0r = ws[WS_BS0 + tid];
  const float bs1r = ws[WS_BS1 + tid];

  float c0r = 0.f, c1r = 0.f;  // cell states (threads tid<128)

  // ---- LDS init ----
  for (int e = tid; e < 8 * 512; e += NTHR) s.wi0[e] = wsu[WS_WI0 + e];
  for (int e = tid; e < KM * HID; e += NTHR) s.wout[e] = Wout[e];
  for (int e = tid; e < ZD * ZD; e += NTHR) s.Q[e] = ws[WS_Q + e];
  if (tid < AD * AD) s.R[tid] = ws[WS_R + tid];
  if (tid < KM) s.bout_s[tid] = bout[tid];
  if (tid < 64) { s.h0p[tid] = 0u; s.h1p[tid] = 0u; }
  #pragma unroll
  for (int q = 0; q < 2; ++q) {
    int e = tid + q * NTHR;
    s.P[(e >> 5) * 33 + (e & 31)] = initc[e];
  }
  if (tid < ZD) s.meanp[tid] = initm[tid];
  if (tid < AD) {
    float v = as_[(size_t)b * AD + tid];
    s.af[tid] = v;
    ((__half*)s.ap)[tid] = __float2half_rn(v);
    o_a[(size_t)b * AD + tid] = v;
  }
  {  // C0 = sum_k CK[k]  (w0 = ones)
    float acc = 0.f;
    #pragma unroll
    for (int k = 0; k < KM; ++k) acc += CK[k * (AD * ZD) + tid];
    s.C[(tid >> 5) * 33 + (tid & 31)] = acc;
    o_Cs[(size_t)b * (AD * ZD) + tid] = acc;
  }
  #pragma unroll
  for (int q = 0; q < 2; ++q) {  // o_As[0] = sum_k AK[k]
    int e = tid + q * NTHR;
    float acc = 0.f;
    #pragma unroll
    for (int k = 0; k < KM; ++k) acc += AK[k * (ZD * ZD) + e];
    o_As[(size_t)b * (ZD * ZD) + e] = acc;
  }
  __syncthreads();

  for (int t = 0; t < T_STEPS; ++t) {
    const size_t tb = (size_t)t * B_SZ + b;
    const size_t tb2 = (size_t)(t + 1) * B_SZ + b;

    // ===== A: L0 gate (streamed f16 weights) + CP = C@P + r =====
    {
      float acc = bs0r;
      #pragma unroll
      for (int k = 0; k < 8; ++k) acc = dot2f(s.ap[k], s.wi0[k * 512 + tid], acc);
      #pragma unroll
      for (int d4 = 0; d4 < 16; ++d4) {
        uint4 w = Wg[d4 * 512 + tid];
        uint4 hv = *(const uint4*)&s.h0p[d4 * 4];
        acc = dot2f(hv.x, w.x, acc);
        acc = dot2f(hv.y, w.y, acc);
        acc = dot2f(hv.z, w.z, acc);
        acc = dot2f(hv.w, w.w, acc);
      }
      s.g[tid] = acc;
    }
    {
      int i = tid >> 5, jj = tid & 31;
      float acc = 0.f;
      #pragma unroll
      for (int k = 0; k < ZD; ++k) acc += s.C[i * 33 + k] * s.P[k * 33 + jj];
      s.CP[i * 33 + jj] = acc;
    }
    if (tid >= 480 && tid < 480 + AD) {
      int i = tid - 480;
      float acc = s.af[i];
      #pragma unroll
      for (int k = 0; k < ZD; ++k) acc -= s.C[i * 33 + k] * s.meanp[k];
      s.r[i] = acc;
    }
    __syncthreads();

    // ===== B: h0/c0 update + S = CP C^T + R =====
    if (tid < HID) {
      float ig = sigm(s.g[tid]);
      float fg = sigm(s.g[HID + tid]);
      float gg = tanhf(s.g[2 * HID + tid]);
      float og = sigm(s.g[3 * HID + tid]);
      c0r = fg * c0r + ig * gg;
      float h0 = og * tanhf(c0r);
      ((__half*)s.h0p)[tid] = __float2half_rn(h0);
    }
    if (tid < AD * AD) {
      int i = tid >> 4, jj = tid & 15;
      float acc = s.R[i * AD + jj];
      #pragma unroll
      for (int k = 0; k < ZD; ++k) acc += s.CP[i * 33 + k] * s.C[jj * 33 + k];
      s.SA[i * 17 + jj] = acc;
    }
    __syncthreads();

    // ===== C: L1 gate (streamed f16 weights) =====
    {
      float acc = bs1r;
      #pragma unroll
      for (int d4 = 0; d4 < 16; ++d4) {
        uint4 w = Wg[(16 + d4) * 512 + tid];
        uint4 hv = *(const uint4*)&s.h0p[d4 * 4];
        acc = dot2f(hv.x, w.x, acc);
        acc = dot2f(hv.y, w.y, acc);
        acc = dot2f(hv.z, w.z, acc);
        acc = dot2f(hv.w, w.w, acc);
      }
      #pragma unroll
      for (int d4 = 0; d4 < 16; ++d4) {
        uint4 w = Wg[(32 + d4) * 512 + tid];
        uint4 hv = *(const uint4*)&s.h1p[d4 * 4];
        acc = dot2f(hv.x, w.x, acc);
        acc = dot2f(hv.y, w.y, acc);
        acc = dot2f(hv.z, w.z, acc);
        acc = dot2f(hv.w, w.w, acc);
      }
      s.g[tid] = acc;
    }
    __syncthreads();

    // ===== D: [tid<128] h1/c1 + logit partials  |  [wave 7] register GJ -> K^T =====
    if (tid < HID) {
      float ig = sigm(s.g[tid]);
      float fg = sigm(s.g[HID + tid]);
      float gg = tanhf(s.g[2 * HID + tid]);
      float og = sigm(s.g[3 * HID + tid]);
      c1r = fg * c1r + ig * gg;
      float h1u = og * tanhf(c1r);
      ((__half*)s.h1p)[tid] = __float2half_rn(h1u);
      int w2 = tid >> 6, lane = tid & 63;
      #pragma unroll
      for (int gi = 0; gi < KM; ++gi) {
        float p = s.wout[gi * HID + tid] * h1u;
        #pragma unroll
        for (int m = 32; m >= 1; m >>= 1) p += __shfl_xor(p, m);
        if (lane == 0) s.lgp[w2 * KM + gi] = p;
      }
    } else if (tid >= 448) {
      // wave-synchronous GJ in registers: lane l holds column l of [S | CP]
      const int l = tid & 63;
      float col[16];
      #pragma unroll
      for (int i = 0; i < AD; ++i)
        col[i] = (l < AD) ? s.SA[i * 17 + l] : s.CP[i * 33 + ((l - AD) & 31)];
      #pragma unroll
      for (int j = 0; j < AD; ++j) {
        float pd = __shfl(col[j], j);
        float pinv = 1.0f / pd;
        float oldj = col[j];
        #pragma unroll
        for (int i = 0; i < AD; ++i) {
          if (i == j) continue;
          float fi = __shfl(col[i], j);
          col[i] = fmaf(-(fi * pinv), oldj, col[i]);
        }
        col[j] = oldj * pinv;
      }
      if (l >= AD && l < AD + ZD) {
        #pragma unroll
        for (int k = 0; k < AD; ++k) s.KT[k * 33 + (l - AD)] = col[k];
      }
    }
    __syncthreads();

    // ===== E: softmax + A_next/C_next einsum + cov_t + mean_t =====
    {
      float lg[KM];
      float mx = -1e30f;
      #pragma unroll
      for (int k = 0; k < KM; ++k) {
        lg[k] = s.lgp[k] + s.lgp[KM + k] + s.bout_s[k];
        mx = fmaxf(mx, lg[k]);
      }
      float sum = 0.f;
      #pragma unroll
      for (int k = 0; k < KM; ++k) { lg[k] = expf(lg[k] - mx); sum += lg[k]; }
      float inv = 1.0f / sum;
      #pragma unroll
      for (int k = 0; k < KM; ++k) lg[k] *= inv;
      #pragma unroll
      for (int q = 0; q < 2; ++q) {
        int e = tid + q * NTHR;
        float acc = 0.f;
        #pragma unroll
        for (int k = 0; k < KM; ++k) acc += lg[k] * AK[k * (ZD * ZD) + e];
        s.An[(e >> 5) * 33 + (e & 31)] = acc;
        o_As[tb2 * (ZD * ZD) + e] = acc;
      }
      {
        float acc = 0.f;
        #pragma unroll
        for (int k = 0; k < KM; ++k) acc += lg[k] * CK[k * (AD * ZD) + tid];
        s.C[(tid >> 5) * 33 + (tid & 31)] = acc;
        o_Cs[tb2 * (AD * ZD) + tid] = acc;
      }
    }
    #pragma unroll
    for (int q = 0; q < 2; ++q) {  // cov_t = P - K @ CP
      int e = tid + q * NTHR;
      int i = e >> 5, jj = e & 31;
      float acc = 0.f;
      #pragma unroll
      for (int k = 0; k < AD; ++k) acc += s.KT[k * 33 + i] * s.CP[k * 33 + jj];
      s.Ct[i * 33 + jj] = s.P[i * 33 + jj] - acc;
    }
    if (tid >= 128 && tid < 128 + ZD) {  // mean_t
      int i = tid - 128;
      float acc = s.meanp[i];
      #pragma unroll
      for (int k = 0; k < AD; ++k) acc += s.KT[k * 33 + i] * s.r[k];
      s.meant[i] = acc;
      o_means[tb * ZD + i] = acc;
    }
    __syncthreads();

    // ===== F: covs out = sym(Ct), ACt = An @ sym(Ct), meanp' = An @ mean_t =====
    #pragma unroll
    for (int q = 0; q < 2; ++q) {
      int e = tid + q * NTHR;
      int i = e >> 5, jj = e & 31;
      o_covs[tb * (ZD * ZD) + e] = 0.5f * (s.Ct[i * 33 + jj] + s.Ct[jj * 33 + i]);
      float acc = 0.f;
      #pragma unroll
      for (int k = 0; k < ZD; ++k)
        acc += s.An[i * 33 + k] * (0.5f * (s.Ct[k * 33 + jj] + s.Ct[jj * 33 + k]));
      s.ACt[i * 33 + jj] = acc;
    }
    if (tid >= 160 && tid < 160 + ZD) {
      int i = tid - 160;
      float acc = 0.f;
      #pragma unroll
      for (int k = 0; k < ZD; ++k) acc += s.An[i * 33 + k] * s.meant[k];
      s.meanp[i] = acc;
      o_nmean[tb * ZD + i] = acc;
    }
    __syncthreads();

    // ===== G: cov_p' = sym(ACt @ An^T) + Q  + a_{t+1} prefetch =====
    #pragma unroll
    for (int q = 0; q < 2; ++q) {
      int e = tid + q * NTHR;
      int i = e >> 5, jj = e & 31;
      float acc = 0.f;
      #pragma unroll
      for (int k = 0; k < ZD; ++k)
        acc += s.ACt[i * 33 + k] * s.An[jj * 33 + k] + s.ACt[jj * 33 + k] * s.An[i * 33 + k];
      float v = 0.5f * acc + s.Q[e];
      s.P[i * 33 + jj] = v;
      o_ncovs[tb * (ZD * ZD) + e] = v;
    }
    if (t < T_STEPS - 1 && tid >= 416 && tid < 416 + AD) {
      int i = tid - 416;
      float v = as_[tb2 * AD + i];
      s.af[i] = v;
      ((__half*)s.ap)[i] = __float2half_rn(v);
      o_a[tb2 * AD + i] = v;
    }
    __syncthreads();
  }
}

extern "C" void kernel_launch(void* const* d_in, const int* in_sizes, int n_in,
                              void* d_out, int out_size, void* d_ws, size_t ws_size,
                              hipStream_t stream) {
  const float* as_ = (const float*)d_in[0];
  const float* AK = (const float*)d_in[1];
  const float* CK = (const float*)d_in[2];
  const float* QL = (const float*)d_in[3];
  const float* RL = (const float*)d_in[4];
  const float* initm = (const float*)d_in[5];
  const float* initc = (const float*)d_in[6];
  const float* Wih0 = (const float*)d_in[7];
  const float* Whh0 = (const float*)d_in[8];
  const float* bih0 = (const float*)d_in[9];
  const float* bhh0 = (const float*)d_in[10];
  const float* Wih1 = (const float*)d_in[11];
  const float* Whh1 = (const float*)d_in[12];
  const float* bih1 = (const float*)d_in[13];
  const float* bhh1 = (const float*)d_in[14];
  const float* Wout = (const float*)d_in[15];
  const float* bout = (const float*)d_in[16];
  float* ws = (float*)d_ws;
  float* out = (float*)d_out;

  ssm_prep_kernel<<<16, 256, 0, stream>>>(Wih0, Whh0, Wih1, Whh1, bih0, bhh0, bih1, bhh1,
                                          QL, RL, ws);
  ssm_main_kernel<<<B_SZ, NTHR, 0, stream>>>(as_, AK, CK, initm, initc, Wout, bout, ws, out);
}

// Round 8
// 2420.975 us; speedup vs baseline: 2.3631x; 1.4116x over previous
//
#include <hip/hip_runtime.h>
#include <hip/hip_fp16.h>
#include <math.h>

#define T_STEPS 128
#define B_SZ 256
#define AD 16
#define ZD 32
#define KM 8
#define HID 128
#define G4H 512
#define NTHR 512
#define LDW 36   // padded stride (dwords) for 32-col fp32 matrices, 16B aligned
#define LDC 20   // padded stride for 16-col K rows (Kk), 16B aligned

// ws layout (4-byte word offsets)
// WS_WQ: 48*512*4 u32, packed f16 pairs, [d4][thread j][m]
//   d4  0..15 : W_hh0 row j; 16..31 : W_ih1 row j; 32..47 : W_hh1 row j
#define WS_WQ   0
#define WS_WI0  98304     // 8*512 u32 : W_ih0 row j packed pairs, [k][j]
#define WS_BS0  102400    // 512  b_ih0+b_hh0
#define WS_BS1  102912    // 512  b_ih1+b_hh1
#define WS_Q    103424    // 1024 Q = QL QL^T + 1e-3 I
#define WS_R    104448    // 256  R = RL RL^T + 1e-3 I

typedef float f32x4 __attribute__((ext_vector_type(4)));

__device__ __forceinline__ unsigned pk16(float lo, float hi) {
  unsigned a = __half_as_ushort(__float2half_rn(lo));
  unsigned b = __half_as_ushort(__float2half_rn(hi));
  return a | (b << 16);
}

__global__ void ssm_prep_kernel(const float* __restrict__ Wih0, const float* __restrict__ Whh0,
                                const float* __restrict__ Wih1, const float* __restrict__ Whh1,
                                const float* __restrict__ bih0, const float* __restrict__ bhh0,
                                const float* __restrict__ bih1, const float* __restrict__ bhh1,
                                const float* __restrict__ QL, const float* __restrict__ RL,
                                float* __restrict__ ws) {
  unsigned* wsu = (unsigned*)ws;
  int tid = blockIdx.x * blockDim.x + threadIdx.x;
  int nt = gridDim.x * blockDim.x;
  for (int j = tid; j < G4H; j += nt) {
    for (int d4 = 0; d4 < 48; ++d4) {
      for (int m = 0; m < 4; ++m) {
        int dd = (d4 & 15) * 4 + m;
        const float* src = (d4 < 16) ? Whh0 : (d4 < 32) ? Wih1 : Whh1;
        wsu[WS_WQ + (d4 * 512 + j) * 4 + m] =
            pk16(src[j * 128 + 2 * dd], src[j * 128 + 2 * dd + 1]);
      }
    }
    for (int k = 0; k < 8; ++k)
      wsu[WS_WI0 + k * 512 + j] = pk16(Wih0[j * 16 + 2 * k], Wih0[j * 16 + 2 * k + 1]);
    ws[WS_BS0 + j] = bih0[j] + bhh0[j];
    ws[WS_BS1 + j] = bih1[j] + bhh1[j];
  }
  for (int e = tid; e < ZD * ZD; e += nt) {
    int i = e >> 5, j = e & 31;
    float s = 0.f;
    for (int k = 0; k < ZD; ++k) s += QL[i * ZD + k] * QL[j * ZD + k];
    if (i == j) s += 0.001f;
    ws[WS_Q + e] = s;
  }
  for (int e = tid; e < AD * AD; e += nt) {
    int i = e >> 4, j = e & 15;
    float s = 0.f;
    for (int k = 0; k < AD; ++k) s += RL[i * AD + k] * RL[j * AD + k];
    if (i == j) s += 0.001f;
    ws[WS_R + e] = s;
  }
}

struct alignas(16) BS {
  unsigned ap[8];            // a_t packed f16 pairs
  float af[AD];              // a_t f32
  unsigned h0p[64];          // h0 packed f16 pairs
  unsigned h1p[64];
  float g[G4H];              // gates
  float lgp[16];             // logit partials
  float meanp[ZD], meant[ZD], r[AD];
  float P[ZD * LDW];         // cov_p
  float An[ZD * LDW];        // A_next
  float Mt[ZD * LDW];        // cov_t (unsym)
  float ACt[ZD * LDW];       // A_next @ sym(cov_t)
  float C[AD * LDW];
  float CP[AD * LDW];
  float Kk[ZD * LDC];        // K row-major 32x16
  float SA[AD * 17];         // S
};

__device__ __forceinline__ float sigm(float x) { return 1.0f / (1.0f + expf(-x)); }
__device__ __forceinline__ float dotv(f32x4 a, f32x4 b) {
  return a[0] * b[0] + a[1] * b[1] + a[2] * b[2] + a[3] * b[3];
}
__device__ __forceinline__ void st_nt(float* p, float v) { __builtin_nontemporal_store(v, p); }
__device__ __forceinline__ void st_nt4(float* p, f32x4 v) {
  __builtin_nontemporal_store(v, (f32x4*)p);
}

__device__ __forceinline__ float dot2f(unsigned a, unsigned b, float c) {
#if __has_builtin(__builtin_amdgcn_fdot2)
  typedef _Float16 h2 __attribute__((ext_vector_type(2)));
  union U { unsigned u; h2 h; };
  U ua, ub; ua.u = a; ub.u = b;
  return __builtin_amdgcn_fdot2(ua.h, ub.h, c, false);
#else
  union U { unsigned u; _Float16 h[2]; };
  U ua, ub; ua.u = a; ub.u = b;
  return c + (float)ua.h[0] * (float)ub.h[0] + (float)ua.h[1] * (float)ub.h[1];
#endif
}

__global__ void __launch_bounds__(NTHR, 2) ssm_main_kernel(
    const float* __restrict__ as_, const float* __restrict__ AK, const float* __restrict__ CK,
    const float* __restrict__ initm, const float* __restrict__ initc,
    const float* __restrict__ Wout, const float* __restrict__ bout,
    const float* __restrict__ ws, float* __restrict__ out) {
  __shared__ BS s;
  const int tid = threadIdx.x;
  const int b = blockIdx.x;
  const unsigned* wsu = (const unsigned*)ws;
  const uint4* Wg = (const uint4*)(wsu + WS_WQ);
  const f32x4* AK4 = (const f32x4*)AK;
  const f32x4* CK4 = (const f32x4*)CK;

  float* o_means = out;
  float* o_covs = o_means + (size_t)T_STEPS * B_SZ * ZD;
  float* o_nmean = o_covs + (size_t)T_STEPS * B_SZ * ZD * ZD;
  float* o_ncovs = o_nmean + (size_t)T_STEPS * B_SZ * ZD;
  float* o_As = o_ncovs + (size_t)T_STEPS * B_SZ * ZD * ZD;
  float* o_Cs = o_As + (size_t)(T_STEPS + 1) * B_SZ * ZD * ZD;
  float* o_a = o_Cs + (size_t)(T_STEPS + 1) * B_SZ * AD * ZD;

  // LDS float4 views
  f32x4* An4 = (f32x4*)s.An;
  f32x4* Mt4 = (f32x4*)s.Mt;
  f32x4* ACt4 = (f32x4*)s.ACt;
  f32x4* C4 = (f32x4*)s.C;
  f32x4* CP4 = (f32x4*)s.CP;
  f32x4* Kk4 = (f32x4*)s.Kk;     // stride 5
  const uint4* h0p4 = (const uint4*)s.h0p;
  const uint4* h1p4 = (const uint4*)s.h1p;
  const uint4* ap4 = (const uint4*)s.ap;
  const f32x4* r4 = (const f32x4*)s.r;
  const f32x4* meant4 = (const f32x4*)s.meant;

  // ---- thread-invariant register preloads ----
  unsigned wi0r[8];
  #pragma unroll
  for (int k = 0; k < 8; ++k) wi0r[k] = wsu[WS_WI0 + k * 512 + tid];
  const float bs0r = ws[WS_BS0 + tid];
  const float bs1r = ws[WS_BS1 + tid];
  const float Qr0 = ws[WS_Q + tid];
  const float Qr1 = ws[WS_Q + tid + NTHR];
  const float Rr = (tid < AD * AD) ? ws[WS_R + tid] : 0.f;
  float woutr[8];
  #pragma unroll
  for (int gi = 0; gi < KM; ++gi) woutr[gi] = (tid < HID) ? Wout[gi * HID + tid] : 0.f;
  float boutr[8];
  #pragma unroll
  for (int k = 0; k < KM; ++k) boutr[k] = bout[k];

  float c0r = 0.f, c1r = 0.f;

  // ---- init ----
  if (tid < 64) { s.h0p[tid] = 0u; s.h1p[tid] = 0u; }
  #pragma unroll
  for (int q = 0; q < 2; ++q) {
    int e = tid + q * NTHR;
    s.P[(e >> 5) * LDW + (e & 31)] = initc[e];
  }
  if (tid < ZD) s.meanp[tid] = initm[tid];
  if (tid < AD) {
    float v = as_[(size_t)b * AD + tid];
    s.af[tid] = v;
    ((__half*)s.ap)[tid] = __float2half_rn(v);
    st_nt(&o_a[(size_t)b * AD + tid], v);
  }
  if (tid < 256) {  // o_As[0] = sum_k AK[k] (w0 = ones)
    f32x4 acc = {0.f, 0.f, 0.f, 0.f};
    #pragma unroll
    for (int k = 0; k < KM; ++k) acc += AK4[k * 256 + tid];
    st_nt4(&o_As[(size_t)b * 1024 + tid * 4], acc);
  } else if (tid < 384) {  // C0 = sum_k CK[k]
    int idx = tid - 256;
    f32x4 acc = {0.f, 0.f, 0.f, 0.f};
    #pragma unroll
    for (int k = 0; k < KM; ++k) acc += CK4[k * 128 + idx];
    C4[(idx >> 3) * 9 + (idx & 7)] = acc;
    st_nt4(&o_Cs[(size_t)b * 512 + idx * 4], acc);
  }
  __syncthreads();

  for (int t = 0; t < T_STEPS; ++t) {
    const size_t tb = (size_t)t * B_SZ + b;
    const size_t tb2 = (size_t)(t + 1) * B_SZ + b;

    // ===== A: L0 gate + CP = C@P + r =====
    {
      float acc = bs0r;
      #pragma unroll
      for (int k4 = 0; k4 < 2; ++k4) {
        uint4 av = ap4[k4];
        acc = dot2f(av.x, wi0r[k4 * 4 + 0], acc);
        acc = dot2f(av.y, wi0r[k4 * 4 + 1], acc);
        acc = dot2f(av.z, wi0r[k4 * 4 + 2], acc);
        acc = dot2f(av.w, wi0r[k4 * 4 + 3], acc);
      }
      #pragma unroll
      for (int d4 = 0; d4 < 16; ++d4) {
        uint4 w = Wg[d4 * 512 + tid];
        uint4 hv = h0p4[d4];
        acc = dot2f(hv.x, w.x, acc);
        acc = dot2f(hv.y, w.y, acc);
        acc = dot2f(hv.z, w.z, acc);
        acc = dot2f(hv.w, w.w, acc);
      }
      s.g[tid] = acc;
    }
    {
      int i = tid >> 5, jj = tid & 31;
      float acc = 0.f;
      #pragma unroll
      for (int k4 = 0; k4 < 8; ++k4) {
        f32x4 cv = C4[i * 9 + k4];
        acc = fmaf(cv[0], s.P[(4 * k4 + 0) * LDW + jj], acc);
        acc = fmaf(cv[1], s.P[(4 * k4 + 1) * LDW + jj], acc);
        acc = fmaf(cv[2], s.P[(4 * k4 + 2) * LDW + jj], acc);
        acc = fmaf(cv[3], s.P[(4 * k4 + 3) * LDW + jj], acc);
      }
      s.CP[i * LDW + jj] = acc;
    }
    if (tid >= 480 && tid < 480 + AD) {  // FIX: restore upper bound (was stomping s.P via r[16..31])
      int i = tid - 480;
      float acc = s.af[i];
      #pragma unroll
      for (int k = 0; k < ZD; ++k) acc -= s.C[i * LDW + k] * s.meanp[k];
      s.r[i] = acc;
    }
    __syncthreads();

    // ===== B: h0/c0 + S = CP C^T + R =====
    if (tid < HID) {
      float ig = sigm(s.g[tid]);
      float fg = sigm(s.g[HID + tid]);
      float gg = tanhf(s.g[2 * HID + tid]);
      float og = sigm(s.g[3 * HID + tid]);
      c0r = fg * c0r + ig * gg;
      ((__half*)s.h0p)[tid] = __float2half_rn(og * tanhf(c0r));
    }
    if (tid < AD * AD) {
      int i = tid >> 4, jj = tid & 15;
      float acc = Rr;
      #pragma unroll
      for (int m4 = 0; m4 < 8; ++m4) acc += dotv(CP4[i * 9 + m4], C4[jj * 9 + m4]);
      s.SA[i * 17 + jj] = acc;
    }
    __syncthreads();

    // ===== C: L1 gate =====
    {
      float acc = bs1r;
      #pragma unroll
      for (int d4 = 0; d4 < 16; ++d4) {
        uint4 w = Wg[(16 + d4) * 512 + tid];
        uint4 hv = h0p4[d4];
        acc = dot2f(hv.x, w.x, acc);
        acc = dot2f(hv.y, w.y, acc);
        acc = dot2f(hv.z, w.z, acc);
        acc = dot2f(hv.w, w.w, acc);
      }
      #pragma unroll
      for (int d4 = 0; d4 < 16; ++d4) {
        uint4 w = Wg[(32 + d4) * 512 + tid];
        uint4 hv = h1p4[d4];
        acc = dot2f(hv.x, w.x, acc);
        acc = dot2f(hv.y, w.y, acc);
        acc = dot2f(hv.z, w.z, acc);
        acc = dot2f(hv.w, w.w, acc);
      }
      s.g[tid] = acc;
    }
    __syncthreads();

    // ===== D: [tid<128] h1/c1 + logits  |  [wave 7] register GJ -> K =====
    if (tid < HID) {
      float ig = sigm(s.g[tid]);
      float fg = sigm(s.g[HID + tid]);
      float gg = tanhf(s.g[2 * HID + tid]);
      float og = sigm(s.g[3 * HID + tid]);
      c1r = fg * c1r + ig * gg;
      float h1u = og * tanhf(c1r);
      ((__half*)s.h1p)[tid] = __float2half_rn(h1u);
      int w2 = tid >> 6, lane = tid & 63;
      #pragma unroll
      for (int gi = 0; gi < KM; ++gi) {
        float p = woutr[gi] * h1u;
        #pragma unroll
        for (int m = 32; m >= 1; m >>= 1) p += __shfl_xor(p, m);
        if (lane == 0) s.lgp[w2 * KM + gi] = p;
      }
    } else if (tid >= 448) {
      const int l = tid & 63;
      float col[16];
      #pragma unroll
      for (int i = 0; i < AD; ++i)
        col[i] = (l < AD) ? s.SA[i * 17 + l] : s.CP[i * LDW + ((l - AD) & 31)];
      #pragma unroll
      for (int j = 0; j < AD; ++j) {
        float pd = __shfl(col[j], j);
        float pinv = 1.0f / pd;
        float oldj = col[j];
        #pragma unroll
        for (int i = 0; i < AD; ++i) {
          if (i == j) continue;
          float fi = __shfl(col[i], j);
          col[i] = fmaf(-(fi * pinv), oldj, col[i]);
        }
        col[j] = oldj * pinv;
      }
      if (l >= AD && l < AD + ZD) {
        int rr = l - AD;  // K row rr
        f32x4 v0 = {col[0], col[1], col[2], col[3]};
        f32x4 v1 = {col[4], col[5], col[6], col[7]};
        f32x4 v2 = {col[8], col[9], col[10], col[11]};
        f32x4 v3 = {col[12], col[13], col[14], col[15]};
        Kk4[rr * 5 + 0] = v0;
        Kk4[rr * 5 + 1] = v1;
        Kk4[rr * 5 + 2] = v2;
        Kk4[rr * 5 + 3] = v3;
      }
    }
    __syncthreads();

    // ===== E: softmax + An/C_next einsums (f32x4) + mean_t + a prefetch =====
    {
      float lg[KM];
      float mx = -1e30f;
      #pragma unroll
      for (int k = 0; k < KM; ++k) {
        lg[k] = s.lgp[k] + s.lgp[KM + k] + boutr[k];
        mx = fmaxf(mx, lg[k]);
      }
      float sum = 0.f;
      #pragma unroll
      for (int k = 0; k < KM; ++k) { lg[k] = expf(lg[k] - mx); sum += lg[k]; }
      float inv = 1.0f / sum;
      #pragma unroll
      for (int k = 0; k < KM; ++k) lg[k] *= inv;
      if (tid < 256) {
        f32x4 acc = {0.f, 0.f, 0.f, 0.f};
        #pragma unroll
        for (int k = 0; k < KM; ++k) acc += lg[k] * AK4[k * 256 + tid];
        An4[(tid >> 3) * 9 + (tid & 7)] = acc;
        st_nt4(&o_As[tb2 * 1024 + tid * 4], acc);
      } else if (tid < 384) {
        int idx = tid - 256;
        f32x4 acc = {0.f, 0.f, 0.f, 0.f};
        #pragma unroll
        for (int k = 0; k < KM; ++k) acc += lg[k] * CK4[k * 128 + idx];
        C4[(idx >> 3) * 9 + (idx & 7)] = acc;
        st_nt4(&o_Cs[tb2 * 512 + idx * 4], acc);
      } else if (tid < 416) {
        int i = tid - 384;  // mean_t
        float acc = s.meanp[i];
        #pragma unroll
        for (int m = 0; m < 4; ++m) acc += dotv(Kk4[i * 5 + m], r4[m]);
        s.meant[i] = acc;
        st_nt(&o_means[tb * ZD + i], acc);
      } else if (tid < 432 && t < T_STEPS - 1) {
        int i = tid - 416;  // a_{t+1}
        float v = as_[tb2 * AD + i];
        s.af[i] = v;
        ((__half*)s.ap)[i] = __float2half_rn(v);
        st_nt(&o_a[tb2 * AD + i], v);
      }
    }
    __syncthreads();

    // ===== F: cov_t = P - K@CP -> Mt  + meanp' = An@mean_t =====
    {
      int i0 = tid >> 5, i1 = i0 + 16, jj = tid & 31;
      f32x4 kr0[4], kr1[4];
      #pragma unroll
      for (int m = 0; m < 4; ++m) { kr0[m] = Kk4[i0 * 5 + m]; kr1[m] = Kk4[i1 * 5 + m]; }
      float a0 = 0.f, a1 = 0.f;
      #pragma unroll
      for (int k4 = 0; k4 < 4; ++k4) {
        #pragma unroll
        for (int m = 0; m < 4; ++m) {
          float cp = s.CP[(4 * k4 + m) * LDW + jj];
          a0 = fmaf(kr0[k4][m], cp, a0);
          a1 = fmaf(kr1[k4][m], cp, a1);
        }
      }
      s.Mt[i0 * LDW + jj] = s.P[i0 * LDW + jj] - a0;
      s.Mt[i1 * LDW + jj] = s.P[i1 * LDW + jj] - a1;
    }
    if (tid >= 480) {
      int i = tid - 480;  // i in [0,32) — meanp has ZD=32 entries, in-bounds
      float acc = 0.f;
      #pragma unroll
      for (int m = 0; m < 8; ++m) acc += dotv(An4[i * 9 + m], meant4[m]);
      s.meanp[i] = acc;
      st_nt(&o_nmean[tb * ZD + i], acc);
    }
    __syncthreads();

    // ===== H: covs out = sym(Mt) + ACt = An @ sym(Mt) =====
    {
      int i0 = tid >> 5, i1 = i0 + 16, jj = tid & 31;
      st_nt(&o_covs[tb * 1024 + tid],
            0.5f * (s.Mt[i0 * LDW + jj] + s.Mt[jj * LDW + i0]));
      st_nt(&o_covs[tb * 1024 + tid + NTHR],
            0.5f * (s.Mt[i1 * LDW + jj] + s.Mt[jj * LDW + i1]));
      float acc0 = 0.f, acc1 = 0.f;
      #pragma unroll
      for (int k4 = 0; k4 < 8; ++k4) {
        f32x4 an0 = An4[i0 * 9 + k4];
        f32x4 an1 = An4[i1 * 9 + k4];
        f32x4 mtj = Mt4[jj * 9 + k4];
        #pragma unroll
        for (int m = 0; m < 4; ++m) {
          float sy = 0.5f * (s.Mt[(4 * k4 + m) * LDW + jj] + mtj[m]);
          acc0 = fmaf(an0[m], sy, acc0);
          acc1 = fmaf(an1[m], sy, acc1);
        }
      }
      s.ACt[i0 * LDW + jj] = acc0;
      s.ACt[i1 * LDW + jj] = acc1;
    }
    __syncthreads();

    // ===== I: cov_p' = sym(ACt @ An^T) + Q -> P (fused, exact-symmetric) =====
    {
      int i0 = tid >> 5, i1 = i0 + 16, jj = tid & 31;
      float acc0 = 0.f, acc1 = 0.f;
      #pragma unroll
      for (int k4 = 0; k4 < 8; ++k4) {
        f32x4 aci0 = ACt4[i0 * 9 + k4];
        f32x4 aci1 = ACt4[i1 * 9 + k4];
        f32x4 acj = ACt4[jj * 9 + k4];
        f32x4 ani0 = An4[i0 * 9 + k4];
        f32x4 ani1 = An4[i1 * 9 + k4];
        f32x4 anj = An4[jj * 9 + k4];
        #pragma unroll
        for (int m = 0; m < 4; ++m) {
          acc0 += aci0[m] * anj[m] + acj[m] * ani0[m];
          acc1 += aci1[m] * anj[m] + acj[m] * ani1[m];
        }
      }
      float v0 = 0.5f * acc0 + Qr0;
      float v1 = 0.5f * acc1 + Qr1;
      s.P[i0 * LDW + jj] = v0;
      s.P[i1 * LDW + jj] = v1;
      st_nt(&o_ncovs[tb * 1024 + tid], v0);
      st_nt(&o_ncovs[tb * 1024 + tid + NTHR], v1);
    }
    __syncthreads();
  }
}

extern "C" void kernel_launch(void* const* d_in, const int* in_sizes, int n_in,
                              void* d_out, int out_size, void* d_ws, size_t ws_size,
                              hipStream_t stream) {
  const float* as_ = (const float*)d_in[0];
  const float* AK = (const float*)d_in[1];
  const float* CK = (const float*)d_in[2];
  const float* QL = (const float*)d_in[3];
  const float* RL = (const float*)d_in[4];
  const float* initm = (const float*)d_in[5];
  const float* initc = (const float*)d_in[6];
  const float* Wih0 = (const float*)d_in[7];
  const float* Whh0 = (const float*)d_in[8];
  const float* bih0 = (const float*)d_in[9];
  const float* bhh0 = (const float*)d_in[10];
  const float* Wih1 = (const float*)d_in[11];
  const float* Whh1 = (const float*)d_in[12];
  const float* bih1 = (const float*)d_in[13];
  const float* bhh1 = (const float*)d_in[14];
  const float* Wout = (const float*)d_in[15];
  const float* bout = (const float*)d_in[16];
  float* ws = (float*)d_ws;
  float* out = (float*)d_out;

  ssm_prep_kernel<<<16, 256, 0, stream>>>(Wih0, Whh0, Wih1, Whh1, bih0, bhh0, bih1, bhh1,
                                          QL, RL, ws);
  ssm_main_kernel<<<B_SZ, NTHR, 0, stream>>>(as_, AK, CK, initm, initc, Wout, bout, ws, out);
}

// Round 9
// 2350.774 us; speedup vs baseline: 2.4337x; 1.0299x over previous
//
#include <hip/hip_runtime.h>
#include <hip/hip_fp16.h>
#include <math.h>

#define T_STEPS 128
#define B_SZ 256
#define AD 16
#define ZD 32
#define KM 8
#define HID 128
#define G4H 512
#define NTHR 512
#define LDW 36   // padded stride (dwords) for 32-col fp32 matrices, 16B aligned
#define LDC 20   // padded stride for 16-col rows (Kk, CPT), 16B aligned

// ws layout (4-byte word offsets)
// WS_WQ: 48*512*4 u32, packed f16 pairs, [d4][thread j][m]
//   d4  0..15 : W_hh0 row j; 16..31 : W_ih1 row j; 32..47 : W_hh1 row j
#define WS_WQ   0
#define WS_WI0  98304     // 8*512 u32 : W_ih0 row j packed pairs, [k][j]
#define WS_BS0  102400    // 512  b_ih0+b_hh0
#define WS_BS1  102912    // 512  b_ih1+b_hh1
#define WS_Q    103424    // 1024 Q = QL QL^T + 1e-3 I
#define WS_R    104448    // 256  R = RL RL^T + 1e-3 I

typedef float f32x4 __attribute__((ext_vector_type(4)));

__device__ __forceinline__ unsigned pk16(float lo, float hi) {
  unsigned a = __half_as_ushort(__float2half_rn(lo));
  unsigned b = __half_as_ushort(__float2half_rn(hi));
  return a | (b << 16);
}

__global__ void ssm_prep_kernel(const float* __restrict__ Wih0, const float* __restrict__ Whh0,
                                const float* __restrict__ Wih1, const float* __restrict__ Whh1,
                                const float* __restrict__ bih0, const float* __restrict__ bhh0,
                                const float* __restrict__ bih1, const float* __restrict__ bhh1,
                                const float* __restrict__ QL, const float* __restrict__ RL,
                                float* __restrict__ ws) {
  unsigned* wsu = (unsigned*)ws;
  int tid = blockIdx.x * blockDim.x + threadIdx.x;
  int nt = gridDim.x * blockDim.x;
  for (int j = tid; j < G4H; j += nt) {
    for (int d4 = 0; d4 < 48; ++d4) {
      for (int m = 0; m < 4; ++m) {
        int dd = (d4 & 15) * 4 + m;
        const float* src = (d4 < 16) ? Whh0 : (d4 < 32) ? Wih1 : Whh1;
        wsu[WS_WQ + (d4 * 512 + j) * 4 + m] =
            pk16(src[j * 128 + 2 * dd], src[j * 128 + 2 * dd + 1]);
      }
    }
    for (int k = 0; k < 8; ++k)
      wsu[WS_WI0 + k * 512 + j] = pk16(Wih0[j * 16 + 2 * k], Wih0[j * 16 + 2 * k + 1]);
    ws[WS_BS0 + j] = bih0[j] + bhh0[j];
    ws[WS_BS1 + j] = bih1[j] + bhh1[j];
  }
  for (int e = tid; e < ZD * ZD; e += nt) {
    int i = e >> 5, j = e & 31;
    float s = 0.f;
    for (int k = 0; k < ZD; ++k) s += QL[i * ZD + k] * QL[j * ZD + k];
    if (i == j) s += 0.001f;
    ws[WS_Q + e] = s;
  }
  for (int e = tid; e < AD * AD; e += nt) {
    int i = e >> 4, j = e & 15;
    float s = 0.f;
    for (int k = 0; k < AD; ++k) s += RL[i * AD + k] * RL[j * AD + k];
    if (i == j) s += 0.001f;
    ws[WS_R + e] = s;
  }
}

struct alignas(16) BS {
  unsigned ap[8];            // a_t packed f16 pairs
  float af[AD];              // a_t f32
  unsigned h0p[64];          // h0 packed f16 pairs
  unsigned h1p[64];
  float g[G4H];              // gates
  float lgp[16];             // logit partials
  float meanp[ZD], meant[ZD], r[AD];
  float P[ZD * LDW];         // cov_p (EXACTLY symmetric by construction)
  float An[ZD * LDW];        // A_next
  float Mt[ZD * LDW];        // cov_t (unsym), rows
  float MtT[ZD * LDW];       // cov_t transpose, rows = Mt columns
  float ACt[ZD * LDW];       // A_next @ sym(cov_t)
  float C[AD * LDW];
  float CP[AD * LDW];        // C @ P, rows (16x32)
  float CPT[ZD * LDC];       // (C @ P)^T, rows (32x16)
  float Kk[ZD * LDC];        // K row-major 32x16
  float SA[AD * 17];         // S
};

__device__ __forceinline__ float sigm(float x) { return 1.0f / (1.0f + expf(-x)); }
__device__ __forceinline__ float dotv(f32x4 a, f32x4 b) {
  return a[0] * b[0] + a[1] * b[1] + a[2] * b[2] + a[3] * b[3];
}
__device__ __forceinline__ void st_nt(float* p, float v) { __builtin_nontemporal_store(v, p); }
__device__ __forceinline__ void st_nt4(float* p, f32x4 v) {
  __builtin_nontemporal_store(v, (f32x4*)p);
}

__device__ __forceinline__ float dot2f(unsigned a, unsigned b, float c) {
#if __has_builtin(__builtin_amdgcn_fdot2)
  typedef _Float16 h2 __attribute__((ext_vector_type(2)));
  union U { unsigned u; h2 h; };
  U ua, ub; ua.u = a; ub.u = b;
  return __builtin_amdgcn_fdot2(ua.h, ub.h, c, false);
#else
  union U { unsigned u; _Float16 h[2]; };
  U ua, ub; ua.u = a; ub.u = b;
  return c + (float)ua.h[0] * (float)ub.h[0] + (float)ua.h[1] * (float)ub.h[1];
#endif
}

__global__ void __launch_bounds__(NTHR, 2) ssm_main_kernel(
    const float* __restrict__ as_, const float* __restrict__ AK, const float* __restrict__ CK,
    const float* __restrict__ initm, const float* __restrict__ initc,
    const float* __restrict__ Wout, const float* __restrict__ bout,
    const float* __restrict__ ws, float* __restrict__ out) {
  __shared__ BS s;
  const int tid = threadIdx.x;
  const int b = blockIdx.x;
  const unsigned* wsu = (const unsigned*)ws;
  const uint4* Wg = (const uint4*)(wsu + WS_WQ);
  const f32x4* AK4 = (const f32x4*)AK;
  const f32x4* CK4 = (const f32x4*)CK;

  float* o_means = out;
  float* o_covs = o_means + (size_t)T_STEPS * B_SZ * ZD;
  float* o_nmean = o_covs + (size_t)T_STEPS * B_SZ * ZD * ZD;
  float* o_ncovs = o_nmean + (size_t)T_STEPS * B_SZ * ZD;
  float* o_As = o_ncovs + (size_t)T_STEPS * B_SZ * ZD * ZD;
  float* o_Cs = o_As + (size_t)(T_STEPS + 1) * B_SZ * ZD * ZD;
  float* o_a = o_Cs + (size_t)(T_STEPS + 1) * B_SZ * AD * ZD;

  // LDS float4 views (row-chunk reads; all strides multiple of 4 dwords)
  f32x4* P4 = (f32x4*)s.P;         // stride 9
  f32x4* An4 = (f32x4*)s.An;
  f32x4* Mt4 = (f32x4*)s.Mt;
  f32x4* MtT4 = (f32x4*)s.MtT;
  f32x4* ACt4 = (f32x4*)s.ACt;
  f32x4* C4 = (f32x4*)s.C;
  f32x4* CP4 = (f32x4*)s.CP;
  f32x4* CPT4 = (f32x4*)s.CPT;     // stride 5
  f32x4* Kk4 = (f32x4*)s.Kk;       // stride 5
  const uint4* h0p4 = (const uint4*)s.h0p;
  const uint4* h1p4 = (const uint4*)s.h1p;
  const uint4* ap4 = (const uint4*)s.ap;
  const f32x4* r4 = (const f32x4*)s.r;
  const f32x4* meant4 = (const f32x4*)s.meant;
  const f32x4* meanp4 = (const f32x4*)s.meanp;

  // ---- thread-invariant register preloads ----
  unsigned wi0r[8];
  #pragma unroll
  for (int k = 0; k < 8; ++k) wi0r[k] = wsu[WS_WI0 + k * 512 + tid];
  // W_hh1 row `tid` persistent in registers: 16 uint4 = 64 VGPRs, compile-time indexed
  uint4 w1r[16];
  #pragma unroll
  for (int d4 = 0; d4 < 16; ++d4) w1r[d4] = Wg[(32 + d4) * 512 + tid];
  const float bs0r = ws[WS_BS0 + tid];
  const float bs1r = ws[WS_BS1 + tid];
  const float Qr0 = ws[WS_Q + tid];
  const float Qr1 = ws[WS_Q + tid + NTHR];
  const float Rr = (tid < AD * AD) ? ws[WS_R + tid] : 0.f;
  float woutr[8];
  #pragma unroll
  for (int gi = 0; gi < KM; ++gi) woutr[gi] = (tid < HID) ? Wout[gi * HID + tid] : 0.f;
  float boutr[8];
  #pragma unroll
  for (int k = 0; k < KM; ++k) boutr[k] = bout[k];

  float c0r = 0.f, c1r = 0.f;

  // ---- init ----
  if (tid < 64) { s.h0p[tid] = 0u; s.h1p[tid] = 0u; }
  #pragma unroll
  for (int q = 0; q < 2; ++q) {
    int e = tid + q * NTHR;
    s.P[(e >> 5) * LDW + (e & 31)] = initc[e];
  }
  if (tid < ZD) s.meanp[tid] = initm[tid];
  if (tid < AD) {
    float v = as_[(size_t)b * AD + tid];
    s.af[tid] = v;
    ((__half*)s.ap)[tid] = __float2half_rn(v);
    st_nt(&o_a[(size_t)b * AD + tid], v);
  }
  if (tid < 256) {  // o_As[0] = sum_k AK[k] (w0 = ones)
    f32x4 acc = {0.f, 0.f, 0.f, 0.f};
    #pragma unroll
    for (int k = 0; k < KM; ++k) acc += AK4[k * 256 + tid];
    st_nt4(&o_As[(size_t)b * 1024 + tid * 4], acc);
  } else if (tid < 384) {  // C0 = sum_k CK[k]
    int idx = tid - 256;
    f32x4 acc = {0.f, 0.f, 0.f, 0.f};
    #pragma unroll
    for (int k = 0; k < KM; ++k) acc += CK4[k * 128 + idx];
    C4[(idx >> 3) * 9 + (idx & 7)] = acc;
    st_nt4(&o_Cs[(size_t)b * 512 + idx * 4], acc);
  }
  __syncthreads();

  for (int t = 0; t < T_STEPS; ++t) {
    const size_t tb = (size_t)t * B_SZ + b;
    const size_t tb2 = (size_t)(t + 1) * B_SZ + b;

    // ===== A: L0 gate + CP = C@P (P symmetric -> row dots) + r =====
    {
      float acc = bs0r;
      #pragma unroll
      for (int k4 = 0; k4 < 2; ++k4) {
        uint4 av = ap4[k4];
        acc = dot2f(av.x, wi0r[k4 * 4 + 0], acc);
        acc = dot2f(av.y, wi0r[k4 * 4 + 1], acc);
        acc = dot2f(av.z, wi0r[k4 * 4 + 2], acc);
        acc = dot2f(av.w, wi0r[k4 * 4 + 3], acc);
      }
      #pragma unroll
      for (int d4 = 0; d4 < 16; ++d4) {
        uint4 w = Wg[d4 * 512 + tid];
        uint4 hv = h0p4[d4];
        acc = dot2f(hv.x, w.x, acc);
        acc = dot2f(hv.y, w.y, acc);
        acc = dot2f(hv.z, w.z, acc);
        acc = dot2f(hv.w, w.w, acc);
      }
      s.g[tid] = acc;
    }
    {
      int i = tid >> 5, jj = tid & 31;
      float acc = 0.f;
      #pragma unroll
      for (int k4 = 0; k4 < 8; ++k4)
        acc += dotv(C4[i * 9 + k4], P4[jj * 9 + k4]);  // P row jj == column jj (symmetric)
      s.CP[i * LDW + jj] = acc;
      s.CPT[jj * LDC + i] = acc;
    }
    if (tid >= 480 && tid < 480 + AD) {
      int i = tid - 480;
      float acc = s.af[i];
      #pragma unroll
      for (int k4 = 0; k4 < 8; ++k4) acc -= dotv(C4[i * 9 + k4], meanp4[k4]);
      s.r[i] = acc;
    }
    __syncthreads();

    // ===== B: h0/c0 + S = CP C^T + R =====
    if (tid < HID) {
      float ig = sigm(s.g[tid]);
      float fg = sigm(s.g[HID + tid]);
      float gg = tanhf(s.g[2 * HID + tid]);
      float og = sigm(s.g[3 * HID + tid]);
      c0r = fg * c0r + ig * gg;
      ((__half*)s.h0p)[tid] = __float2half_rn(og * tanhf(c0r));
    }
    if (tid < AD * AD) {
      int i = tid >> 4, jj = tid & 15;
      float acc = Rr;
      #pragma unroll
      for (int m4 = 0; m4 < 8; ++m4) acc += dotv(CP4[i * 9 + m4], C4[jj * 9 + m4]);
      s.SA[i * 17 + jj] = acc;
    }
    __syncthreads();

    // ===== C: L1 gate (W_ih1 streamed, W_hh1 from registers) =====
    {
      float acc = bs1r;
      #pragma unroll
      for (int d4 = 0; d4 < 16; ++d4) {
        uint4 w = Wg[(16 + d4) * 512 + tid];
        uint4 hv = h0p4[d4];
        acc = dot2f(hv.x, w.x, acc);
        acc = dot2f(hv.y, w.y, acc);
        acc = dot2f(hv.z, w.z, acc);
        acc = dot2f(hv.w, w.w, acc);
      }
      #pragma unroll
      for (int d4 = 0; d4 < 16; ++d4) {
        uint4 hv = h1p4[d4];
        acc = dot2f(hv.x, w1r[d4].x, acc);
        acc = dot2f(hv.y, w1r[d4].y, acc);
        acc = dot2f(hv.z, w1r[d4].z, acc);
        acc = dot2f(hv.w, w1r[d4].w, acc);
      }
      s.g[tid] = acc;
    }
    __syncthreads();

    // ===== D: [tid<128] h1/c1 + logits  |  [wave 7] register GJ -> K =====
    if (tid < HID) {
      float ig = sigm(s.g[tid]);
      float fg = sigm(s.g[HID + tid]);
      float gg = tanhf(s.g[2 * HID + tid]);
      float og = sigm(s.g[3 * HID + tid]);
      c1r = fg * c1r + ig * gg;
      float h1u = og * tanhf(c1r);
      ((__half*)s.h1p)[tid] = __float2half_rn(h1u);
      int w2 = tid >> 6, lane = tid & 63;
      #pragma unroll
      for (int gi = 0; gi < KM; ++gi) {
        float p = woutr[gi] * h1u;
        #pragma unroll
        for (int m = 32; m >= 1; m >>= 1) p += __shfl_xor(p, m);
        if (lane == 0) s.lgp[w2 * KM + gi] = p;
      }
    } else if (tid >= 448) {
      const int l = tid & 63;
      float col[16];
      #pragma unroll
      for (int i = 0; i < AD; ++i)
        col[i] = (l < AD) ? s.SA[i * 17 + l] : s.CP[i * LDW + ((l - AD) & 31)];
      #pragma unroll
      for (int j = 0; j < AD; ++j) {
        float pd = __shfl(col[j], j);
        float pinv = 1.0f / pd;
        float oldj = col[j];
        #pragma unroll
        for (int i = 0; i < AD; ++i) {
          if (i == j) continue;
          float fi = __shfl(col[i], j);
          col[i] = fmaf(-(fi * pinv), oldj, col[i]);
        }
        col[j] = oldj * pinv;
      }
      if (l >= AD && l < AD + ZD) {
        int rr = l - AD;  // K row rr
        f32x4 v0 = {col[0], col[1], col[2], col[3]};
        f32x4 v1 = {col[4], col[5], col[6], col[7]};
        f32x4 v2 = {col[8], col[9], col[10], col[11]};
        f32x4 v3 = {col[12], col[13], col[14], col[15]};
        Kk4[rr * 5 + 0] = v0;
        Kk4[rr * 5 + 1] = v1;
        Kk4[rr * 5 + 2] = v2;
        Kk4[rr * 5 + 3] = v3;
      }
    }
    __syncthreads();

    // ===== E: softmax + An/C_next einsums + mean_t + a prefetch =====
    {
      float lg[KM];
      float mx = -1e30f;
      #pragma unroll
      for (int k = 0; k < KM; ++k) {
        lg[k] = s.lgp[k] + s.lgp[KM + k] + boutr[k];
        mx = fmaxf(mx, lg[k]);
      }
      float sum = 0.f;
      #pragma unroll
      for (int k = 0; k < KM; ++k) { lg[k] = expf(lg[k] - mx); sum += lg[k]; }
      float inv = 1.0f / sum;
      #pragma unroll
      for (int k = 0; k < KM; ++k) lg[k] *= inv;
      if (tid < 256) {
        f32x4 acc = {0.f, 0.f, 0.f, 0.f};
        #pragma unroll
        for (int k = 0; k < KM; ++k) acc += lg[k] * AK4[k * 256 + tid];
        An4[(tid >> 3) * 9 + (tid & 7)] = acc;
        st_nt4(&o_As[tb2 * 1024 + tid * 4], acc);
      } else if (tid < 384) {
        int idx = tid - 256;
        f32x4 acc = {0.f, 0.f, 0.f, 0.f};
        #pragma unroll
        for (int k = 0; k < KM; ++k) acc += lg[k] * CK4[k * 128 + idx];
        C4[(idx >> 3) * 9 + (idx & 7)] = acc;
        st_nt4(&o_Cs[tb2 * 512 + idx * 4], acc);
      } else if (tid < 416) {
        int i = tid - 384;  // mean_t
        float acc = s.meanp[i];
        #pragma unroll
        for (int m = 0; m < 4; ++m) acc += dotv(Kk4[i * 5 + m], r4[m]);
        s.meant[i] = acc;
        st_nt(&o_means[tb * ZD + i], acc);
      } else if (tid < 432 && t < T_STEPS - 1) {
        int i = tid - 416;  // a_{t+1}
        float v = as_[tb2 * AD + i];
        s.af[i] = v;
        ((__half*)s.ap)[i] = __float2half_rn(v);
        st_nt(&o_a[tb2 * AD + i], v);
      }
    }
    __syncthreads();

    // ===== F: cov_t = P - K@CP -> Mt + MtT  +  meanp' = An@mean_t =====
    {
      int i0 = tid >> 5, i1 = i0 + 16, jj = tid & 31;
      f32x4 cpt[4];
      #pragma unroll
      for (int m = 0; m < 4; ++m) cpt[m] = CPT4[jj * 5 + m];  // CP column jj
      float a0 = 0.f, a1 = 0.f;
      #pragma unroll
      for (int m = 0; m < 4; ++m) {
        a0 += dotv(Kk4[i0 * 5 + m], cpt[m]);
        a1 += dotv(Kk4[i1 * 5 + m], cpt[m]);
      }
      float m0 = s.P[i0 * LDW + jj] - a0;
      float m1 = s.P[i1 * LDW + jj] - a1;
      s.Mt[i0 * LDW + jj] = m0;
      s.Mt[i1 * LDW + jj] = m1;
      s.MtT[jj * LDW + i0] = m0;
      s.MtT[jj * LDW + i1] = m1;
    }
    if (tid >= 480) {
      int i = tid - 480;  // i in [0,32)
      float acc = 0.f;
      #pragma unroll
      for (int m = 0; m < 8; ++m) acc += dotv(An4[i * 9 + m], meant4[m]);
      s.meanp[i] = acc;
      st_nt(&o_nmean[tb * ZD + i], acc);
    }
    __syncthreads();

    // ===== H: covs out = sym(Mt) (f32x4 NT) + ACt = An @ sym(Mt) (row dots) =====
    if (tid < 256) {
      int i = tid >> 3, j4 = tid & 7;
      f32x4 sym = 0.5f * (Mt4[i * 9 + j4] + MtT4[i * 9 + j4]);
      st_nt4(&o_covs[tb * 1024 + i * 32 + j4 * 4], sym);
    }
    {
      int i0 = tid >> 5, i1 = i0 + 16, jj = tid & 31;
      float acc0 = 0.f, acc1 = 0.f;
      #pragma unroll
      for (int k4 = 0; k4 < 8; ++k4) {
        // symMt row jj chunk k4 (symMt symmetric -> row == column)
        f32x4 sy = 0.5f * (Mt4[jj * 9 + k4] + MtT4[jj * 9 + k4]);
        acc0 += dotv(An4[i0 * 9 + k4], sy);
        acc1 += dotv(An4[i1 * 9 + k4], sy);
      }
      s.ACt[i0 * LDW + jj] = acc0;
      s.ACt[i1 * LDW + jj] = acc1;
    }
    __syncthreads();

    // ===== I: cov_p' = sym(ACt @ An^T) + Q -> P (fused, exact-symmetric) =====
    {
      int i0 = tid >> 5, i1 = i0 + 16, jj = tid & 31;
      float acc0 = 0.f, acc1 = 0.f;
      #pragma unroll
      for (int k4 = 0; k4 < 8; ++k4) {
        f32x4 anj = An4[jj * 9 + k4];
        f32x4 acj = ACt4[jj * 9 + k4];
        acc0 += dotv(ACt4[i0 * 9 + k4], anj) + dotv(acj, An4[i0 * 9 + k4]);
        acc1 += dotv(ACt4[i1 * 9 + k4], anj) + dotv(acj, An4[i1 * 9 + k4]);
      }
      float v0 = 0.5f * acc0 + Qr0;
      float v1 = 0.5f * acc1 + Qr1;
      s.P[i0 * LDW + jj] = v0;
      s.P[i1 * LDW + jj] = v1;
      st_nt(&o_ncovs[tb * 1024 + tid], v0);
      st_nt(&o_ncovs[tb * 1024 + tid + NTHR], v1);
    }
    __syncthreads();
  }
}

extern "C" void kernel_launch(void* const* d_in, const int* in_sizes, int n_in,
                              void* d_out, int out_size, void* d_ws, size_t ws_size,
                              hipStream_t stream) {
  const float* as_ = (const float*)d_in[0];
  const float* AK = (const float*)d_in[1];
  const float* CK = (const float*)d_in[2];
  const float* QL = (const float*)d_in[3];
  const float* RL = (const float*)d_in[4];
  const float* initm = (const float*)d_in[5];
  const float* initc = (const float*)d_in[6];
  const float* Wih0 = (const float*)d_in[7];
  const float* Whh0 = (const float*)d_in[8];
  const float* bih0 = (const float*)d_in[9];
  const float* bhh0 = (const float*)d_in[10];
  const float* Wih1 = (const float*)d_in[11];
  const float* Whh1 = (const float*)d_in[12];
  const float* bih1 = (const float*)d_in[13];
  const float* bhh1 = (const float*)d_in[14];
  const float* Wout = (const float*)d_in[15];
  const float* bout = (const float*)d_in[16];
  float* ws = (float*)d_ws;
  float* out = (float*)d_out;

  ssm_prep_kernel<<<16, 256, 0, stream>>>(Wih0, Whh0, Wih1, Whh1, bih0, bhh0, bih1, bhh1,
                                          QL, RL, ws);
  ssm_main_kernel<<<B_SZ, NTHR, 0, stream>>>(as_, AK, CK, initm, initc, Wout, bout, ws, out);
}